// Round 1
// baseline (840.815 us; speedup 1.0000x reference)
//
#include <hip/hip_runtime.h>
#include <math.h>

#define BATCH  2
#define SEQ    1024
#define HIDDEN 1024
#define NHEADS 8
#define DHEAD  128
#define NTOK   (BATCH*SEQ)
#define GEPS   1e-5f

// ---------------------------------------------------------------------------
// gamma decay table: gpow[h][k] = gamma_h ^ k
// ---------------------------------------------------------------------------
__global__ void gpow_kernel(float* __restrict__ gpow) {
    const int h = blockIdx.x;
    const int k = threadIdx.x;
    const float l = fmaf((float)h, -0.39608410317711170f, -3.46573590279972650f);
    const float gamma = 1.0f - expf(l);
    gpow[h*SEQ + k] = powf(gamma, (float)k);
}

// ---------------------------------------------------------------------------
// per-head projections + RoPE phases:
//   qre/qim = (Xh@Wq)*exp(i n'theta); kre/kim = (Xh@Wk)*exp(-i n'theta); v = Xh@Wv
// Layout of outputs: [token][HIDDEN] with head block at h*DHEAD.
// ---------------------------------------------------------------------------
__global__ __launch_bounds__(256) void proj_kernel(
    const float* __restrict__ X,
    const float* __restrict__ Wq, const float* __restrict__ Wk, const float* __restrict__ Wv,
    const float* __restrict__ theta,
    float* __restrict__ qre, float* __restrict__ qim,
    float* __restrict__ kre, float* __restrict__ kim,
    float* __restrict__ vv)
{
    const int tt  = blockIdx.x;   // 64-token tile
    const int h   = blockIdx.y;
    const int mt  = blockIdx.z;   // 0:q 1:k 2:v
    const int tid = threadIdx.x;

    __shared__ __align__(16) float Xs[64][132];

    for (int i = tid*4; i < 64*128; i += 1024) {
        const int r = i >> 7, c = i & 127;
        *(float4*)&Xs[r][c] = *(const float4*)&X[(size_t)(tt*64 + r)*HIDDEN + h*DHEAD + c];
    }
    __syncthreads();

    const float* W = ((mt == 0) ? Wq : (mt == 1) ? Wk : Wv) + (size_t)h*DHEAD*DHEAD;
    const int tx = tid & 31, ty = tid >> 5;

    float a0[8], a1[8], a2[8], a3[8];
    #pragma unroll
    for (int j = 0; j < 8; ++j) { a0[j]=0.f; a1[j]=0.f; a2[j]=0.f; a3[j]=0.f; }

    #pragma unroll 4
    for (int k = 0; k < DHEAD; ++k) {
        const float4 w = *(const float4*)&W[k*DHEAD + tx*4];
        #pragma unroll
        for (int j = 0; j < 8; ++j) {
            const float x = Xs[ty*8 + j][k];
            a0[j] = fmaf(x, w.x, a0[j]);
            a1[j] = fmaf(x, w.y, a1[j]);
            a2[j] = fmaf(x, w.z, a2[j]);
            a3[j] = fmaf(x, w.w, a3[j]);
        }
    }

    const int d0 = tx*4;
    const float th0 = theta[h*DHEAD + d0 + 0];
    const float th1 = theta[h*DHEAD + d0 + 1];
    const float th2 = theta[h*DHEAD + d0 + 2];
    const float th3 = theta[h*DHEAD + d0 + 3];

    #pragma unroll
    for (int j = 0; j < 8; ++j) {
        const int t = tt*64 + ty*8 + j;
        const size_t g = (size_t)t*HIDDEN + h*DHEAD + d0;
        if (mt == 2) {
            float4 o; o.x=a0[j]; o.y=a1[j]; o.z=a2[j]; o.w=a3[j];
            *(float4*)&vv[g] = o;
        } else {
            const float np1 = (float)((t & (SEQ-1)) + 1);
            float s0,c0,s1,c1,s2,c2,s3,c3;
            sincosf(np1*th0, &s0, &c0);
            sincosf(np1*th1, &s1, &c1);
            sincosf(np1*th2, &s2, &c2);
            sincosf(np1*th3, &s3, &c3);
            float4 re, im;
            re.x = a0[j]*c0; re.y = a1[j]*c1; re.z = a2[j]*c2; re.w = a3[j]*c3;
            if (mt == 0) {
                im.x = a0[j]*s0; im.y = a1[j]*s1; im.z = a2[j]*s2; im.w = a3[j]*s3;
                *(float4*)&qre[g] = re;
                *(float4*)&qim[g] = im;
            } else {
                im.x = -a0[j]*s0; im.y = -a1[j]*s1; im.z = -a2[j]*s2; im.w = -a3[j]*s3;
                *(float4*)&kre[g] = re;
                *(float4*)&kim[g] = im;
            }
        }
    }
}

// ---------------------------------------------------------------------------
// retention attention: per (b,h, 32-query tile) loop over causal 32-key tiles.
//   s[n][m] = (sum_d Q K) * gamma^(n-m), masked; Y += s @ V  (complex s, real V)
// ---------------------------------------------------------------------------
#define CDOT4(SR, SI, QR, QI, KR, KI) \
    SR = fmaf((QR).x, (KR).x, SR); SR = fmaf(-(QI).x, (KI).x, SR); \
    SI = fmaf((QR).x, (KI).x, SI); SI = fmaf((QI).x, (KR).x, SI); \
    SR = fmaf((QR).y, (KR).y, SR); SR = fmaf(-(QI).y, (KI).y, SR); \
    SI = fmaf((QR).y, (KI).y, SI); SI = fmaf((QI).y, (KR).y, SI); \
    SR = fmaf((QR).z, (KR).z, SR); SR = fmaf(-(QI).z, (KI).z, SR); \
    SI = fmaf((QR).z, (KI).z, SI); SI = fmaf((QI).z, (KR).z, SI); \
    SR = fmaf((QR).w, (KR).w, SR); SR = fmaf(-(QI).w, (KI).w, SR); \
    SI = fmaf((QR).w, (KI).w, SI); SI = fmaf((QI).w, (KR).w, SI);

__global__ __launch_bounds__(256) void attn_kernel(
    const float* __restrict__ qre, const float* __restrict__ qim,
    const float* __restrict__ kre, const float* __restrict__ kim,
    const float* __restrict__ vv,  const float* __restrict__ gpow,
    float* __restrict__ yre, float* __restrict__ yim)
{
    const int qt  = blockIdx.x;
    const int b   = blockIdx.y >> 3;
    const int h   = blockIdx.y & 7;
    const int tid = threadIdx.x;

    __shared__ __align__(16) float Qre[32][132];
    __shared__ __align__(16) float Qim[32][132];
    __shared__ __align__(16) float sre_s[32][33];
    __shared__ __align__(16) float sim_s[32][33];
    __shared__ __align__(16) float KV[32*128];     // union: K chunk (re/im) | V tile

    float* __restrict__ Kre_s = KV;                // [32][36]
    float* __restrict__ Kim_s = KV + 32*36;        // [32][36]

    const size_t bh = (size_t)b*SEQ*HIDDEN + h*DHEAD;

    for (int i = tid*4; i < 32*128; i += 1024) {
        const int r = i >> 7, c = i & 127;
        const size_t g = bh + (size_t)(qt*32 + r)*HIDDEN + c;
        *(float4*)&Qre[r][c] = *(const float4*)&qre[g];
        *(float4*)&Qim[r][c] = *(const float4*)&qim[g];
    }

    const int yr = tid & 31, yg = tid >> 5;
    float ayr[16], ayi[16];
    #pragma unroll
    for (int j = 0; j < 16; ++j) { ayr[j]=0.f; ayi[j]=0.f; }

    const int ty = tid >> 4, tx = tid & 15;
    const float* gp = gpow + h*SEQ;

    for (int mt = 0; mt <= qt; ++mt) {
        float sr00=0.f, sr01=0.f, sr10=0.f, sr11=0.f;
        float si00=0.f, si01=0.f, si10=0.f, si11=0.f;

        #pragma unroll 1
        for (int ck = 0; ck < 4; ++ck) {
            __syncthreads();   // protects KV reuse (prev AV reads / prev chunk reads; also Q load on first pass)
            {
                const int r = tid >> 3, c4 = (tid & 7)*4;
                const size_t g = bh + (size_t)(mt*32 + r)*HIDDEN + ck*32 + c4;
                *(float4*)&Kre_s[r*36 + c4] = *(const float4*)&kre[g];
                *(float4*)&Kim_s[r*36 + c4] = *(const float4*)&kim[g];
            }
            __syncthreads();
            #pragma unroll
            for (int k4 = 0; k4 < 32; k4 += 4) {
                const int kk = ck*32 + k4;
                const float4 q0r = *(const float4*)&Qre[ty][kk];
                const float4 q0i = *(const float4*)&Qim[ty][kk];
                const float4 q1r = *(const float4*)&Qre[ty+16][kk];
                const float4 q1i = *(const float4*)&Qim[ty+16][kk];
                const float4 k0r = *(const float4*)&Kre_s[tx*36 + k4];
                const float4 k0i = *(const float4*)&Kim_s[tx*36 + k4];
                const float4 k1r = *(const float4*)&Kre_s[(tx+16)*36 + k4];
                const float4 k1i = *(const float4*)&Kim_s[(tx+16)*36 + k4];
                CDOT4(sr00, si00, q0r, q0i, k0r, k0i);
                CDOT4(sr01, si01, q0r, q0i, k1r, k1i);
                CDOT4(sr10, si10, q1r, q1i, k0r, k0i);
                CDOT4(sr11, si11, q1r, q1i, k1r, k1i);
            }
        }

        // causal decay + mask, stage scores in LDS
        {
            const int q0 = qt*32 + ty;
            const int q1 = q0 + 16;
            const int m0 = mt*32 + tx;
            const int m1 = m0 + 16;
            const int d00 = q0 - m0, d01 = q0 - m1, d10 = q1 - m0, d11 = q1 - m1;
            const float w00 = (d00 >= 0) ? gp[d00] : 0.f;
            const float w01 = (d01 >= 0) ? gp[d01] : 0.f;
            const float w10 = (d10 >= 0) ? gp[d10] : 0.f;
            const float w11 = (d11 >= 0) ? gp[d11] : 0.f;
            sre_s[ty][tx]       = sr00*w00;  sim_s[ty][tx]       = si00*w00;
            sre_s[ty][tx+16]    = sr01*w01;  sim_s[ty][tx+16]    = si01*w01;
            sre_s[ty+16][tx]    = sr10*w10;  sim_s[ty+16][tx]    = si10*w10;
            sre_s[ty+16][tx+16] = sr11*w11;  sim_s[ty+16][tx+16] = si11*w11;
        }
        __syncthreads();   // scores visible + all K-chunk reads done before V overwrites KV

        for (int i = tid*4; i < 32*128; i += 1024) {
            const int r = i >> 7, c = i & 127;
            *(float4*)&KV[r*128 + c] = *(const float4*)&vv[bh + (size_t)(mt*32 + r)*HIDDEN + c];
        }
        __syncthreads();

        #pragma unroll 4
        for (int m = 0; m < 32; ++m) {
            const float pr = sre_s[yr][m];
            const float pi = sim_s[yr][m];
            const float* vrow = &KV[m*128 + yg*16];
            #pragma unroll
            for (int j4 = 0; j4 < 16; j4 += 4) {
                const float4 v4 = *(const float4*)&vrow[j4];
                ayr[j4+0] = fmaf(pr, v4.x, ayr[j4+0]);
                ayr[j4+1] = fmaf(pr, v4.y, ayr[j4+1]);
                ayr[j4+2] = fmaf(pr, v4.z, ayr[j4+2]);
                ayr[j4+3] = fmaf(pr, v4.w, ayr[j4+3]);
                ayi[j4+0] = fmaf(pi, v4.x, ayi[j4+0]);
                ayi[j4+1] = fmaf(pi, v4.y, ayi[j4+1]);
                ayi[j4+2] = fmaf(pi, v4.z, ayi[j4+2]);
                ayi[j4+3] = fmaf(pi, v4.w, ayi[j4+3]);
            }
        }
        // next iteration's leading __syncthreads() protects KV/sre_s
    }

    const size_t g = bh + (size_t)(qt*32 + yr)*HIDDEN + yg*16;
    #pragma unroll
    for (int j4 = 0; j4 < 16; j4 += 4) {
        float4 o1; o1.x=ayr[j4]; o1.y=ayr[j4+1]; o1.z=ayr[j4+2]; o1.w=ayr[j4+3];
        float4 o2; o2.x=ayi[j4]; o2.y=ayi[j4+1]; o2.z=ayi[j4+2]; o2.w=ayi[j4+3];
        *(float4*)&yre[g + j4] = o1;
        *(float4*)&yim[g + j4] = o2;
    }
}

// ---------------------------------------------------------------------------
// complex group norm over each (token, head) group of 128 channels, in-place.
// var = sum(|z-mu|^2)/(HEAD-1); z = (z-mu)/sqrt(var+eps); z = z*w + b (b real)
// ---------------------------------------------------------------------------
__global__ __launch_bounds__(256) void gnorm_kernel(
    float* __restrict__ yre, float* __restrict__ yim,
    const float* __restrict__ w, const float* __restrict__ bbv)
{
    const int g    = blockIdx.x*4 + (threadIdx.x >> 6);
    const int lane = threadIdx.x & 63;
    const int t = g >> 3, h = g & 7;
    const size_t base = (size_t)t*HIDDEN + h*DHEAD;

    const float r0 = yre[base + lane];
    const float r1 = yre[base + lane + 64];
    const float i0 = yim[base + lane];
    const float i1 = yim[base + lane + 64];

    float sr = r0 + r1, si = i0 + i1;
    #pragma unroll
    for (int off = 32; off > 0; off >>= 1) {
        sr += __shfl_xor(sr, off);
        si += __shfl_xor(si, off);
    }
    const float mr = sr * (1.0f/128.0f), mi = si * (1.0f/128.0f);
    const float d0r = r0 - mr, d1r = r1 - mr, d0i = i0 - mi, d1i = i1 - mi;
    float vs = d0r*d0r + d0i*d0i + d1r*d1r + d1i*d1i;
    #pragma unroll
    for (int off = 32; off > 0; off >>= 1) vs += __shfl_xor(vs, off);
    const float scale = 1.0f / sqrtf(vs * (1.0f/127.0f) + GEPS);

    const float w0 = w[h*DHEAD + lane],   w1 = w[h*DHEAD + lane + 64];
    const float b0 = bbv[h*DHEAD + lane], b1 = bbv[h*DHEAD + lane + 64];
    yre[base + lane]      = fmaf(d0r*scale, w0, b0);
    yre[base + lane + 64] = fmaf(d1r*scale, w1, b1);
    yim[base + lane]      = d0i*scale*w0;
    yim[base + lane + 64] = d1i*scale*w1;
}

// ---------------------------------------------------------------------------
// G = X @ (Wg_re + i Wg_im); G = G * sigmoid(G)  (complex swish); store re/im
// ---------------------------------------------------------------------------
__global__ __launch_bounds__(256) void gswish_kernel(
    const float* __restrict__ X,
    const float* __restrict__ Wgre, const float* __restrict__ Wgim,
    float* __restrict__ gre, float* __restrict__ gim)
{
    const int tt  = blockIdx.x;   // 64 rows
    const int ct  = blockIdx.y;   // 64 cols
    const int tid = threadIdx.x;
    const int tx = tid & 15, ty = tid >> 4;

    __shared__ __align__(16) float Xt[32][68];   // transposed [k][row]
    __shared__ __align__(16) float Wr[32][64];
    __shared__ __align__(16) float Wi[32][64];

    float ar[4][4], ai[4][4];
    #pragma unroll
    for (int i2 = 0; i2 < 4; ++i2)
        #pragma unroll
        for (int j = 0; j < 4; ++j) { ar[i2][j]=0.f; ai[i2][j]=0.f; }

    for (int kk = 0; kk < HIDDEN; kk += 32) {
        __syncthreads();
        for (int i = tid*4; i < 64*32; i += 1024) {
            const int r = i >> 5, c = i & 31;
            const float4 x4 = *(const float4*)&X[(size_t)(tt*64 + r)*HIDDEN + kk + c];
            Xt[c+0][r] = x4.x; Xt[c+1][r] = x4.y; Xt[c+2][r] = x4.z; Xt[c+3][r] = x4.w;
        }
        for (int i = tid*4; i < 32*64; i += 1024) {
            const int r = i >> 6, c = i & 63;
            *(float4*)&Wr[r][c] = *(const float4*)&Wgre[(size_t)(kk + r)*HIDDEN + ct*64 + c];
            *(float4*)&Wi[r][c] = *(const float4*)&Wgim[(size_t)(kk + r)*HIDDEN + ct*64 + c];
        }
        __syncthreads();
        #pragma unroll 8
        for (int k = 0; k < 32; ++k) {
            const float4 x4  = *(const float4*)&Xt[k][ty*4];
            const float4 wr4 = *(const float4*)&Wr[k][tx*4];
            const float4 wi4 = *(const float4*)&Wi[k][tx*4];
            const float xv[4]  = {x4.x, x4.y, x4.z, x4.w};
            const float wrv[4] = {wr4.x, wr4.y, wr4.z, wr4.w};
            const float wiv[4] = {wi4.x, wi4.y, wi4.z, wi4.w};
            #pragma unroll
            for (int i2 = 0; i2 < 4; ++i2)
                #pragma unroll
                for (int j = 0; j < 4; ++j) {
                    ar[i2][j] = fmaf(xv[i2], wrv[j], ar[i2][j]);
                    ai[i2][j] = fmaf(xv[i2], wiv[j], ai[i2][j]);
                }
        }
    }

    #pragma unroll
    for (int i2 = 0; i2 < 4; ++i2) {
        const size_t row = tt*64 + ty*4 + i2;
        float outr[4], outi[4];
        #pragma unroll
        for (int j = 0; j < 4; ++j) {
            const float grv = ar[i2][j], giv = ai[i2][j];
            const float e = expf(-grv);
            float sg, cg;
            sincosf(giv, &sg, &cg);
            const float wrv = fmaf(e, cg, 1.0f);   // 1 + e^{-gr} cos(gi)
            const float wiv = -e*sg;               // -e^{-gr} sin(gi)
            const float inv = 1.0f / fmaf(wrv, wrv, wiv*wiv);
            outr[j] = (grv*wrv + giv*wiv)*inv;
            outi[j] = (giv*wrv - grv*wiv)*inv;
        }
        float4 o1; o1.x=outr[0]; o1.y=outr[1]; o1.z=outr[2]; o1.w=outr[3];
        float4 o2; o2.x=outi[0]; o2.y=outi[1]; o2.z=outi[2]; o2.w=outi[3];
        *(float4*)&gre[row*HIDDEN + ct*64 + tx*4] = o1;
        *(float4*)&gim[row*HIDDEN + ct*64 + tx*4] = o2;
    }
}

// ---------------------------------------------------------------------------
// out = (G + Y) @ (Wo_re + i Wo_im); store real part (cplx=0) or interleaved
// ---------------------------------------------------------------------------
__global__ __launch_bounds__(256) void out_kernel(
    const float* __restrict__ gre, const float* __restrict__ gim,
    const float* __restrict__ yre, const float* __restrict__ yim,
    const float* __restrict__ Wore, const float* __restrict__ Woim,
    float* __restrict__ outp, const int cplx)
{
    const int tt  = blockIdx.x;
    const int ct  = blockIdx.y;
    const int tid = threadIdx.x;
    const int tx = tid & 15, ty = tid >> 4;

    __shared__ __align__(16) float Zr[32][68];   // transposed [k][row]
    __shared__ __align__(16) float Zi[32][68];
    __shared__ __align__(16) float Wr[32][64];
    __shared__ __align__(16) float Wi[32][64];

    float ar[4][4], ai[4][4];
    #pragma unroll
    for (int i2 = 0; i2 < 4; ++i2)
        #pragma unroll
        for (int j = 0; j < 4; ++j) { ar[i2][j]=0.f; ai[i2][j]=0.f; }

    for (int kk = 0; kk < HIDDEN; kk += 32) {
        __syncthreads();
        for (int i = tid*4; i < 64*32; i += 1024) {
            const int r = i >> 5, c = i & 31;
            const size_t g = (size_t)(tt*64 + r)*HIDDEN + kk + c;
            const float4 g4r = *(const float4*)&gre[g];
            const float4 y4r = *(const float4*)&yre[g];
            const float4 g4i = *(const float4*)&gim[g];
            const float4 y4i = *(const float4*)&yim[g];
            Zr[c+0][r] = g4r.x + y4r.x; Zr[c+1][r] = g4r.y + y4r.y;
            Zr[c+2][r] = g4r.z + y4r.z; Zr[c+3][r] = g4r.w + y4r.w;
            Zi[c+0][r] = g4i.x + y4i.x; Zi[c+1][r] = g4i.y + y4i.y;
            Zi[c+2][r] = g4i.z + y4i.z; Zi[c+3][r] = g4i.w + y4i.w;
        }
        for (int i = tid*4; i < 32*64; i += 1024) {
            const int r = i >> 6, c = i & 63;
            *(float4*)&Wr[r][c] = *(const float4*)&Wore[(size_t)(kk + r)*HIDDEN + ct*64 + c];
            *(float4*)&Wi[r][c] = *(const float4*)&Woim[(size_t)(kk + r)*HIDDEN + ct*64 + c];
        }
        __syncthreads();
        #pragma unroll 4
        for (int k = 0; k < 32; ++k) {
            const float4 zr4 = *(const float4*)&Zr[k][ty*4];
            const float4 zi4 = *(const float4*)&Zi[k][ty*4];
            const float4 wr4 = *(const float4*)&Wr[k][tx*4];
            const float4 wi4 = *(const float4*)&Wi[k][tx*4];
            const float zrv[4] = {zr4.x, zr4.y, zr4.z, zr4.w};
            const float ziv[4] = {zi4.x, zi4.y, zi4.z, zi4.w};
            const float wrv[4] = {wr4.x, wr4.y, wr4.z, wr4.w};
            const float wiv[4] = {wi4.x, wi4.y, wi4.z, wi4.w};
            #pragma unroll
            for (int i2 = 0; i2 < 4; ++i2)
                #pragma unroll
                for (int j = 0; j < 4; ++j) {
                    ar[i2][j] = fmaf(zrv[i2], wrv[j], ar[i2][j]);
                    ar[i2][j] = fmaf(-ziv[i2], wiv[j], ar[i2][j]);
                    ai[i2][j] = fmaf(zrv[i2], wiv[j], ai[i2][j]);
                    ai[i2][j] = fmaf(ziv[i2], wrv[j], ai[i2][j]);
                }
        }
    }

    #pragma unroll
    for (int i2 = 0; i2 < 4; ++i2) {
        const size_t row = tt*64 + ty*4 + i2;
        const int col = ct*64 + tx*4;
        if (cplx) {
            #pragma unroll
            for (int j = 0; j < 4; ++j) {
                outp[(row*HIDDEN + col + j)*2 + 0] = ar[i2][j];
                outp[(row*HIDDEN + col + j)*2 + 1] = ai[i2][j];
            }
        } else {
            float4 o; o.x=ar[i2][0]; o.y=ar[i2][1]; o.z=ar[i2][2]; o.w=ar[i2][3];
            *(float4*)&outp[row*HIDDEN + col] = o;
        }
    }
}

// ---------------------------------------------------------------------------
extern "C" void kernel_launch(void* const* d_in, const int* in_sizes, int n_in,
                              void* d_out, int out_size, void* d_ws, size_t ws_size,
                              hipStream_t stream)
{
    (void)in_sizes; (void)n_in; (void)ws_size;

    const float* X     = (const float*)d_in[0];
    const float* Wq    = (const float*)d_in[1];
    const float* Wk    = (const float*)d_in[2];
    const float* Wv    = (const float*)d_in[3];
    const float* theta = (const float*)d_in[4];
    const float* gnw   = (const float*)d_in[5];
    const float* gnb   = (const float*)d_in[6];
    const float* Wgre  = (const float*)d_in[7];
    const float* Wgim  = (const float*)d_in[8];
    const float* Wore  = (const float*)d_in[9];
    const float* Woim  = (const float*)d_in[10];

    float* ws = (float*)d_ws;
    const size_t P = (size_t)NTOK*HIDDEN;
    float* qre = ws + 0*P;
    float* qim = ws + 1*P;
    float* kre = ws + 2*P;
    float* kim = ws + 3*P;
    float* vv  = ws + 4*P;
    float* yre = ws + 5*P;
    float* yim = ws + 6*P;
    float* gpw = ws + 7*P;
    float* gre = qre;   // q buffers dead after attn -> reuse for G
    float* gim = qim;

    hipLaunchKernelGGL(gpow_kernel, dim3(NHEADS), dim3(SEQ), 0, stream, gpw);
    hipLaunchKernelGGL(proj_kernel, dim3(NTOK/64, NHEADS, 3), dim3(256), 0, stream,
                       X, Wq, Wk, Wv, theta, qre, qim, kre, kim, vv);
    hipLaunchKernelGGL(attn_kernel, dim3(SEQ/32, BATCH*NHEADS), dim3(256), 0, stream,
                       qre, qim, kre, kim, vv, gpw, yre, yim);
    hipLaunchKernelGGL(gnorm_kernel, dim3(NTOK*NHEADS/4), dim3(256), 0, stream,
                       yre, yim, gnw, gnb);
    hipLaunchKernelGGL(gswish_kernel, dim3(NTOK/64, HIDDEN/64), dim3(256), 0, stream,
                       X, Wgre, Wgim, gre, gim);
    const int cplx = (out_size >= (int)(2*P)) ? 1 : 0;
    hipLaunchKernelGGL(out_kernel, dim3(NTOK/64, HIDDEN/64), dim3(256), 0, stream,
                       gre, gim, yre, yim, Wore, Woim, (float*)d_out, cplx);
}

// Round 2
// 489.341 us; speedup vs baseline: 1.7183x; 1.7183x over previous
//
#include <hip/hip_runtime.h>
#include <math.h>

#define BATCH  2
#define SEQ    1024
#define HIDDEN 1024
#define NHEADS 8
#define DHEAD  128
#define NTOK   (BATCH*SEQ)
#define GEPS   1e-5f

typedef float f32x16 __attribute__((ext_vector_type(16)));
typedef __bf16 bf16x8 __attribute__((ext_vector_type(8)));
typedef unsigned int u32x4 __attribute__((ext_vector_type(4)));

union Frag { u32x4 u; bf16x8 h; };

__device__ __forceinline__ unsigned short f2bf(float f) {
    unsigned int u = __float_as_uint(f);
    unsigned int r = (u + 0x7FFFu + ((u >> 16) & 1u)) >> 16;
    return (unsigned short)r;
}

// ---------------------------------------------------------------------------
// gamma decay table: gpow[h][k] = gamma_h ^ k
// ---------------------------------------------------------------------------
__global__ void gpow_kernel(float* __restrict__ gpow) {
    const int h = blockIdx.x;
    const int k = threadIdx.x;
    const float l = fmaf((float)h, -0.39608410317711170f, -3.46573590279972650f);
    const float gamma = 1.0f - expf(l);
    gpow[h*SEQ + k] = powf(gamma, (float)k);
}

// ---------------------------------------------------------------------------
// per-head projections + RoPE phases -> bf16 Q,K; fp32 V.
// ---------------------------------------------------------------------------
__global__ __launch_bounds__(256) void proj_kernel(
    const float* __restrict__ X,
    const float* __restrict__ Wq, const float* __restrict__ Wk, const float* __restrict__ Wv,
    const float* __restrict__ theta,
    unsigned short* __restrict__ Qbre, unsigned short* __restrict__ Qbim,
    unsigned short* __restrict__ Kbre, unsigned short* __restrict__ Kbim,
    float* __restrict__ vv)
{
    const int tt  = blockIdx.x;   // 64-token tile
    const int h   = blockIdx.y;
    const int mt  = blockIdx.z;   // 0:q 1:k 2:v
    const int tid = threadIdx.x;

    __shared__ __align__(16) float Xs[64][132];

    for (int i = tid*4; i < 64*128; i += 1024) {
        const int r = i >> 7, c = i & 127;
        *(float4*)&Xs[r][c] = *(const float4*)&X[(size_t)(tt*64 + r)*HIDDEN + h*DHEAD + c];
    }
    __syncthreads();

    const float* W = ((mt == 0) ? Wq : (mt == 1) ? Wk : Wv) + (size_t)h*DHEAD*DHEAD;
    const int tx = tid & 31, ty = tid >> 5;

    float a0[8], a1[8], a2[8], a3[8];
    #pragma unroll
    for (int j = 0; j < 8; ++j) { a0[j]=0.f; a1[j]=0.f; a2[j]=0.f; a3[j]=0.f; }

    #pragma unroll 4
    for (int k = 0; k < DHEAD; ++k) {
        const float4 w = *(const float4*)&W[k*DHEAD + tx*4];
        #pragma unroll
        for (int j = 0; j < 8; ++j) {
            const float x = Xs[ty*8 + j][k];
            a0[j] = fmaf(x, w.x, a0[j]);
            a1[j] = fmaf(x, w.y, a1[j]);
            a2[j] = fmaf(x, w.z, a2[j]);
            a3[j] = fmaf(x, w.w, a3[j]);
        }
    }

    const int d0 = tx*4;
    const float th0 = theta[h*DHEAD + d0 + 0];
    const float th1 = theta[h*DHEAD + d0 + 1];
    const float th2 = theta[h*DHEAD + d0 + 2];
    const float th3 = theta[h*DHEAD + d0 + 3];

    #pragma unroll
    for (int j = 0; j < 8; ++j) {
        const int t = tt*64 + ty*8 + j;
        const size_t g = (size_t)t*HIDDEN + h*DHEAD + d0;
        if (mt == 2) {
            float4 o; o.x=a0[j]; o.y=a1[j]; o.z=a2[j]; o.w=a3[j];
            *(float4*)&vv[g] = o;
        } else {
            const float np1 = (float)((t & (SEQ-1)) + 1);
            float s0,c0,s1,c1,s2,c2,s3,c3;
            sincosf(np1*th0, &s0, &c0);
            sincosf(np1*th1, &s1, &c1);
            sincosf(np1*th2, &s2, &c2);
            sincosf(np1*th3, &s3, &c3);
            float rex = a0[j]*c0, rey = a1[j]*c1, rez = a2[j]*c2, rew = a3[j]*c3;
            float imx, imy, imz, imw;
            if (mt == 0) { imx = a0[j]*s0; imy = a1[j]*s1; imz = a2[j]*s2; imw = a3[j]*s3; }
            else         { imx = -a0[j]*s0; imy = -a1[j]*s1; imz = -a2[j]*s2; imw = -a3[j]*s3; }
            ushort4 o1 = make_ushort4(f2bf(rex), f2bf(rey), f2bf(rez), f2bf(rew));
            ushort4 o2 = make_ushort4(f2bf(imx), f2bf(imy), f2bf(imz), f2bf(imw));
            if (mt == 0) { *(ushort4*)&Qbre[g] = o1; *(ushort4*)&Qbim[g] = o2; }
            else         { *(ushort4*)&Kbre[g] = o1; *(ushort4*)&Kbim[g] = o2; }
        }
    }
}

// ---------------------------------------------------------------------------
// V transpose: vv fp32 [token][h*128+d] -> Vtb bf16 [bh][d][s]
// ---------------------------------------------------------------------------
__global__ __launch_bounds__(256) void vt_kernel(
    const float* __restrict__ vv, unsigned short* __restrict__ Vtb)
{
    const int st  = blockIdx.x;   // 32 token-tiles of 64
    const int h   = blockIdx.y;   // 8
    const int tid = threadIdx.x;
    const int b  = st >> 4;
    const int s0 = (st & 15)*64;

    __shared__ __align__(16) float Vs[64][132];

    for (int i = tid*4; i < 64*128; i += 1024) {
        const int r = i >> 7, c = i & 127;
        *(float4*)&Vs[r][c] = *(const float4*)&vv[(size_t)(st*64 + r)*HIDDEN + h*DHEAD + c];
    }
    __syncthreads();

    const int d = tid & 127, seg = tid >> 7;
    unsigned short* dst = Vtb + ((size_t)((b*NHEADS + h)*DHEAD + d))*SEQ + s0 + seg*32;
    #pragma unroll
    for (int j = 0; j < 32; j += 2) {
        unsigned int u = (unsigned)f2bf(Vs[seg*32+j][d]) | ((unsigned)f2bf(Vs[seg*32+j+1][d]) << 16);
        *(unsigned int*)(dst + j) = u;
    }
}

// ---------------------------------------------------------------------------
// retention attention, MFMA bf16. 1 wave per block; 32 queries per wave.
// S^T = mfma(A=K, B=Q) (complex via 4 mfma); decay in fp32 on acc;
// P^T frags assembled in-register via cvt_pk + permlane32_swap;
// Y^T = mfma(A=V^T, B=P^T); transposed store via 17KB LDS tile.
// ---------------------------------------------------------------------------
#define CVTPK(dst, a, b) asm("v_cvt_pk_bf16_f32 %0, %1, %2" : "=v"(dst) : "v"(a), "v"(b))
#define SWAP32(x, y)     asm("v_permlane32_swap_b32 %0, %1" : "+v"(x), "+v"(y))

__global__ __launch_bounds__(64) void attn_kernel(
    const unsigned short* __restrict__ Qbre, const unsigned short* __restrict__ Qbim,
    const unsigned short* __restrict__ Kbre, const unsigned short* __restrict__ Kbim,
    const unsigned short* __restrict__ Vtb,  const float* __restrict__ gpow,
    float* __restrict__ yre, float* __restrict__ yim)
{
    const int lane = threadIdx.x;
    const int l31 = lane & 31, hi = lane >> 5;
    const int qt = blockIdx.x;
    const int bh = blockIdx.y;
    const int b = bh >> 3, h = bh & 7;
    const int q0 = qt * 32;
    const size_t bhoff = (size_t)b*SEQ*HIDDEN + h*DHEAD;
    const float* gp = gpow + h*SEQ;

    __shared__ float Yt2[32][133];

    // per-lane constants: crow(r,hi) and gamma^(-crow)
    int   crw[16];
    float ginv[16];
    #pragma unroll
    for (int r = 0; r < 16; ++r) {
        const int cr = (r & 3) + 8*(r >> 2) + 4*hi;
        crw[r] = cr;
        ginv[r] = 1.0f / gp[cr];
    }

    // Q fragments (B-operand: lane -> q row = l31, d chunk = 16*ks + 8*hi)
    Frag Qr[8], Qi[8];
    {
        const unsigned short* qr = Qbre + bhoff + (size_t)(q0 + l31)*HIDDEN + 8*hi;
        const unsigned short* qi = Qbim + bhoff + (size_t)(q0 + l31)*HIDDEN + 8*hi;
        #pragma unroll
        for (int ks = 0; ks < 8; ++ks) {
            Qr[ks].u = *(const u32x4*)(qr + 16*ks);
            Qi[ks].u = *(const u32x4*)(qi + 16*ks);
        }
    }

    f32x16 Yr[4], Yi[4];
    #pragma unroll
    for (int dt = 0; dt < 4; ++dt)
        #pragma unroll
        for (int e = 0; e < 16; ++e) { Yr[dt][e] = 0.f; Yi[dt][e] = 0.f; }

    #pragma unroll 1
    for (int m = 0; m <= qt; ++m) {
        const int kv0 = m*32;

        // K fragments (A-operand: lane -> key row = l31, d chunk = 16*ks + 8*hi)
        Frag Kr[8], Ki[8];
        {
            const unsigned short* kr = Kbre + bhoff + (size_t)(kv0 + l31)*HIDDEN + 8*hi;
            const unsigned short* ki = Kbim + bhoff + (size_t)(kv0 + l31)*HIDDEN + 8*hi;
            #pragma unroll
            for (int ks = 0; ks < 8; ++ks) {
                Kr[ks].u = *(const u32x4*)(kr + 16*ks);
                Ki[ks].u = *(const u32x4*)(ki + 16*ks);
            }
        }
        // V^T fragments (A-operand: lane -> d row = 32*dt + l31, key chunk = 16*ks2 + 8*hi)
        Frag Vf[4][2];
        #pragma unroll
        for (int dt = 0; dt < 4; ++dt)
            #pragma unroll
            for (int ks2 = 0; ks2 < 2; ++ks2)
                Vf[dt][ks2].u = *(const u32x4*)(Vtb + ((size_t)(bh*DHEAD + dt*32 + l31))*SEQ
                                                + kv0 + 16*ks2 + 8*hi);

        const int  base = 32*(qt - m) + l31;     // n - m at crow=0
        const float g1  = gp[base];

        // scores S^T[key][q]
        f32x16 SR, SI;
        #pragma unroll
        for (int e = 0; e < 16; ++e) { SR[e] = 0.f; SI[e] = 0.f; }
        #pragma unroll
        for (int ks = 0; ks < 8; ++ks) {
            Frag Qin;
            #pragma unroll
            for (int e = 0; e < 4; ++e) Qin.u[e] = Qi[ks].u[e] ^ 0x80008000u;
            SR = __builtin_amdgcn_mfma_f32_32x32x16_bf16(Kr[ks].h, Qr[ks].h, SR, 0, 0, 0);
            SI = __builtin_amdgcn_mfma_f32_32x32x16_bf16(Kr[ks].h, Qi[ks].h, SI, 0, 0, 0);
            SR = __builtin_amdgcn_mfma_f32_32x32x16_bf16(Ki[ks].h, Qin.h, SR, 0, 0, 0);
            SI = __builtin_amdgcn_mfma_f32_32x32x16_bf16(Ki[ks].h, Qr[ks].h, SI, 0, 0, 0);
        }

        // decay + causal mask (only diagonal tile can go negative)
        float pr[16], pi[16];
        #pragma unroll
        for (int r = 0; r < 16; ++r) {
            const float w = (base >= crw[r]) ? g1*ginv[r] : 0.0f;
            pr[r] = SR[r]*w;
            pi[r] = SI[r]*w;
        }

        // cvt_pk + permlane32_swap -> P^T B-fragments (2 ksteps of 16 keys)
        Frag PR[2], PI[2];
        #pragma unroll
        for (int ks2 = 0; ks2 < 2; ++ks2) {
            const int o = ks2*8;
            unsigned int a0, b0, a1, b1;
            CVTPK(a0, pr[o+0], pr[o+1]);
            CVTPK(b0, pr[o+4], pr[o+5]);
            SWAP32(a0, b0);
            CVTPK(a1, pr[o+2], pr[o+3]);
            CVTPK(b1, pr[o+6], pr[o+7]);
            SWAP32(a1, b1);
            PR[ks2].u[0] = a0; PR[ks2].u[1] = a1; PR[ks2].u[2] = b0; PR[ks2].u[3] = b1;
            CVTPK(a0, pi[o+0], pi[o+1]);
            CVTPK(b0, pi[o+4], pi[o+5]);
            SWAP32(a0, b0);
            CVTPK(a1, pi[o+2], pi[o+3]);
            CVTPK(b1, pi[o+6], pi[o+7]);
            SWAP32(a1, b1);
            PI[ks2].u[0] = a0; PI[ks2].u[1] = a1; PI[ks2].u[2] = b0; PI[ks2].u[3] = b1;
        }

        // Y^T += V^T . P^T
        #pragma unroll
        for (int dt = 0; dt < 4; ++dt) {
            Yr[dt] = __builtin_amdgcn_mfma_f32_32x32x16_bf16(Vf[dt][0].h, PR[0].h, Yr[dt], 0, 0, 0);
            Yr[dt] = __builtin_amdgcn_mfma_f32_32x32x16_bf16(Vf[dt][1].h, PR[1].h, Yr[dt], 0, 0, 0);
            Yi[dt] = __builtin_amdgcn_mfma_f32_32x32x16_bf16(Vf[dt][0].h, PI[0].h, Yi[dt], 0, 0, 0);
            Yi[dt] = __builtin_amdgcn_mfma_f32_32x32x16_bf16(Vf[dt][1].h, PI[1].h, Yi[dt], 0, 0, 0);
        }
    }

    // transposed store via LDS (stride 133: conflict-free)
    #pragma unroll
    for (int part = 0; part < 2; ++part) {
        __syncthreads();
        #pragma unroll
        for (int dt = 0; dt < 4; ++dt)
            #pragma unroll
            for (int r = 0; r < 16; ++r)
                Yt2[l31][dt*32 + crw[r]] = part ? Yi[dt][r] : Yr[dt][r];
        __syncthreads();
        const int t = lane >> 1, half = lane & 1;
        float* dst = (part ? yim : yre) + bhoff + (size_t)(q0 + t)*HIDDEN + 64*half;
        #pragma unroll
        for (int j = 0; j < 16; ++j) {
            float4 o;
            o.x = Yt2[t][64*half + 4*j + 0];
            o.y = Yt2[t][64*half + 4*j + 1];
            o.z = Yt2[t][64*half + 4*j + 2];
            o.w = Yt2[t][64*half + 4*j + 3];
            *(float4*)(dst + 4*j) = o;
        }
    }
}

// ---------------------------------------------------------------------------
// complex group norm over each (token, head) group of 128 channels, in-place.
// ---------------------------------------------------------------------------
__global__ __launch_bounds__(256) void gnorm_kernel(
    float* __restrict__ yre, float* __restrict__ yim,
    const float* __restrict__ w, const float* __restrict__ bbv)
{
    const int g    = blockIdx.x*4 + (threadIdx.x >> 6);
    const int lane = threadIdx.x & 63;
    const int t = g >> 3, h = g & 7;
    const size_t base = (size_t)t*HIDDEN + h*DHEAD;

    const float r0 = yre[base + lane];
    const float r1 = yre[base + lane + 64];
    const float i0 = yim[base + lane];
    const float i1 = yim[base + lane + 64];

    float sr = r0 + r1, si = i0 + i1;
    #pragma unroll
    for (int off = 32; off > 0; off >>= 1) {
        sr += __shfl_xor(sr, off);
        si += __shfl_xor(si, off);
    }
    const float mr = sr * (1.0f/128.0f), mi = si * (1.0f/128.0f);
    const float d0r = r0 - mr, d1r = r1 - mr, d0i = i0 - mi, d1i = i1 - mi;
    float vs = d0r*d0r + d0i*d0i + d1r*d1r + d1i*d1i;
    #pragma unroll
    for (int off = 32; off > 0; off >>= 1) vs += __shfl_xor(vs, off);
    const float scale = 1.0f / sqrtf(vs * (1.0f/127.0f) + GEPS);

    const float w0 = w[h*DHEAD + lane],   w1 = w[h*DHEAD + lane + 64];
    const float b0 = bbv[h*DHEAD + lane], b1 = bbv[h*DHEAD + lane + 64];
    yre[base + lane]      = fmaf(d0r*scale, w0, b0);
    yre[base + lane + 64] = fmaf(d1r*scale, w1, b1);
    yim[base + lane]      = d0i*scale*w0;
    yim[base + lane + 64] = d1i*scale*w1;
}

// ---------------------------------------------------------------------------
// G = X @ (Wg_re + i Wg_im); G = G * sigmoid(G)  (complex swish); store re/im
// ---------------------------------------------------------------------------
__global__ __launch_bounds__(256) void gswish_kernel(
    const float* __restrict__ X,
    const float* __restrict__ Wgre, const float* __restrict__ Wgim,
    float* __restrict__ gre, float* __restrict__ gim)
{
    const int tt  = blockIdx.x;   // 64 rows
    const int ct  = blockIdx.y;   // 64 cols
    const int tid = threadIdx.x;
    const int tx = tid & 15, ty = tid >> 4;

    __shared__ __align__(16) float Xt[32][68];   // transposed [k][row]
    __shared__ __align__(16) float Wr[32][64];
    __shared__ __align__(16) float Wi[32][64];

    float ar[4][4], ai[4][4];
    #pragma unroll
    for (int i2 = 0; i2 < 4; ++i2)
        #pragma unroll
        for (int j = 0; j < 4; ++j) { ar[i2][j]=0.f; ai[i2][j]=0.f; }

    for (int kk = 0; kk < HIDDEN; kk += 32) {
        __syncthreads();
        for (int i = tid*4; i < 64*32; i += 1024) {
            const int r = i >> 5, c = i & 31;
            const float4 x4 = *(const float4*)&X[(size_t)(tt*64 + r)*HIDDEN + kk + c];
            Xt[c+0][r] = x4.x; Xt[c+1][r] = x4.y; Xt[c+2][r] = x4.z; Xt[c+3][r] = x4.w;
        }
        for (int i = tid*4; i < 32*64; i += 1024) {
            const int r = i >> 6, c = i & 63;
            *(float4*)&Wr[r][c] = *(const float4*)&Wgre[(size_t)(kk + r)*HIDDEN + ct*64 + c];
            *(float4*)&Wi[r][c] = *(const float4*)&Wgim[(size_t)(kk + r)*HIDDEN + ct*64 + c];
        }
        __syncthreads();
        #pragma unroll 8
        for (int k = 0; k < 32; ++k) {
            const float4 x4  = *(const float4*)&Xt[k][ty*4];
            const float4 wr4 = *(const float4*)&Wr[k][tx*4];
            const float4 wi4 = *(const float4*)&Wi[k][tx*4];
            const float xv[4]  = {x4.x, x4.y, x4.z, x4.w};
            const float wrv[4] = {wr4.x, wr4.y, wr4.z, wr4.w};
            const float wiv[4] = {wi4.x, wi4.y, wi4.z, wi4.w};
            #pragma unroll
            for (int i2 = 0; i2 < 4; ++i2)
                #pragma unroll
                for (int j = 0; j < 4; ++j) {
                    ar[i2][j] = fmaf(xv[i2], wrv[j], ar[i2][j]);
                    ai[i2][j] = fmaf(xv[i2], wiv[j], ai[i2][j]);
                }
        }
    }

    #pragma unroll
    for (int i2 = 0; i2 < 4; ++i2) {
        const size_t row = tt*64 + ty*4 + i2;
        float outr[4], outi[4];
        #pragma unroll
        for (int j = 0; j < 4; ++j) {
            const float grv = ar[i2][j], giv = ai[i2][j];
            const float e = expf(-grv);
            float sg, cg;
            sincosf(giv, &sg, &cg);
            const float wrv = fmaf(e, cg, 1.0f);   // 1 + e^{-gr} cos(gi)
            const float wiv = -e*sg;               // -e^{-gr} sin(gi)
            const float inv = 1.0f / fmaf(wrv, wrv, wiv*wiv);
            outr[j] = (grv*wrv + giv*wiv)*inv;
            outi[j] = (giv*wrv - grv*wiv)*inv;
        }
        float4 o1; o1.x=outr[0]; o1.y=outr[1]; o1.z=outr[2]; o1.w=outr[3];
        float4 o2; o2.x=outi[0]; o2.y=outi[1]; o2.z=outi[2]; o2.w=outi[3];
        *(float4*)&gre[row*HIDDEN + ct*64 + tx*4] = o1;
        *(float4*)&gim[row*HIDDEN + ct*64 + tx*4] = o2;
    }
}

// ---------------------------------------------------------------------------
// out = (G + Y) @ (Wo_re + i Wo_im); store real part (cplx=0) or interleaved
// ---------------------------------------------------------------------------
__global__ __launch_bounds__(256) void out_kernel(
    const float* __restrict__ gre, const float* __restrict__ gim,
    const float* __restrict__ yre, const float* __restrict__ yim,
    const float* __restrict__ Wore, const float* __restrict__ Woim,
    float* __restrict__ outp, const int cplx)
{
    const int tt  = blockIdx.x;
    const int ct  = blockIdx.y;
    const int tid = threadIdx.x;
    const int tx = tid & 15, ty = tid >> 4;

    __shared__ __align__(16) float Zr[32][68];   // transposed [k][row]
    __shared__ __align__(16) float Zi[32][68];
    __shared__ __align__(16) float Wr[32][64];
    __shared__ __align__(16) float Wi[32][64];

    float ar[4][4], ai[4][4];
    #pragma unroll
    for (int i2 = 0; i2 < 4; ++i2)
        #pragma unroll
        for (int j = 0; j < 4; ++j) { ar[i2][j]=0.f; ai[i2][j]=0.f; }

    for (int kk = 0; kk < HIDDEN; kk += 32) {
        __syncthreads();
        for (int i = tid*4; i < 64*32; i += 1024) {
            const int r = i >> 5, c = i & 31;
            const size_t g = (size_t)(tt*64 + r)*HIDDEN + kk + c;
            const float4 g4r = *(const float4*)&gre[g];
            const float4 y4r = *(const float4*)&yre[g];
            const float4 g4i = *(const float4*)&gim[g];
            const float4 y4i = *(const float4*)&yim[g];
            Zr[c+0][r] = g4r.x + y4r.x; Zr[c+1][r] = g4r.y + y4r.y;
            Zr[c+2][r] = g4r.z + y4r.z; Zr[c+3][r] = g4r.w + y4r.w;
            Zi[c+0][r] = g4i.x + y4i.x; Zi[c+1][r] = g4i.y + y4i.y;
            Zi[c+2][r] = g4i.z + y4i.z; Zi[c+3][r] = g4i.w + y4i.w;
        }
        for (int i = tid*4; i < 32*64; i += 1024) {
            const int r = i >> 6, c = i & 63;
            *(float4*)&Wr[r][c] = *(const float4*)&Wore[(size_t)(kk + r)*HIDDEN + ct*64 + c];
            *(float4*)&Wi[r][c] = *(const float4*)&Woim[(size_t)(kk + r)*HIDDEN + ct*64 + c];
        }
        __syncthreads();
        #pragma unroll 4
        for (int k = 0; k < 32; ++k) {
            const float4 zr4 = *(const float4*)&Zr[k][ty*4];
            const float4 zi4 = *(const float4*)&Zi[k][ty*4];
            const float4 wr4 = *(const float4*)&Wr[k][tx*4];
            const float4 wi4 = *(const float4*)&Wi[k][tx*4];
            const float zrv[4] = {zr4.x, zr4.y, zr4.z, zr4.w};
            const float ziv[4] = {zi4.x, zi4.y, zi4.z, zi4.w};
            const float wrv[4] = {wr4.x, wr4.y, wr4.z, wr4.w};
            const float wiv[4] = {wi4.x, wi4.y, wi4.z, wi4.w};
            #pragma unroll
            for (int i2 = 0; i2 < 4; ++i2)
                #pragma unroll
                for (int j = 0; j < 4; ++j) {
                    ar[i2][j] = fmaf(zrv[i2], wrv[j], ar[i2][j]);
                    ar[i2][j] = fmaf(-ziv[i2], wiv[j], ar[i2][j]);
                    ai[i2][j] = fmaf(zrv[i2], wiv[j], ai[i2][j]);
                    ai[i2][j] = fmaf(ziv[i2], wrv[j], ai[i2][j]);
                }
        }
    }

    #pragma unroll
    for (int i2 = 0; i2 < 4; ++i2) {
        const size_t row = tt*64 + ty*4 + i2;
        const int col = ct*64 + tx*4;
        if (cplx) {
            #pragma unroll
            for (int j = 0; j < 4; ++j) {
                outp[(row*HIDDEN + col + j)*2 + 0] = ar[i2][j];
                outp[(row*HIDDEN + col + j)*2 + 1] = ai[i2][j];
            }
        } else {
            float4 o; o.x=ar[i2][0]; o.y=ar[i2][1]; o.z=ar[i2][2]; o.w=ar[i2][3];
            *(float4*)&outp[row*HIDDEN + col] = o;
        }
    }
}

// ---------------------------------------------------------------------------
extern "C" void kernel_launch(void* const* d_in, const int* in_sizes, int n_in,
                              void* d_out, int out_size, void* d_ws, size_t ws_size,
                              hipStream_t stream)
{
    (void)in_sizes; (void)n_in; (void)ws_size;

    const float* X     = (const float*)d_in[0];
    const float* Wq    = (const float*)d_in[1];
    const float* Wk    = (const float*)d_in[2];
    const float* Wv    = (const float*)d_in[3];
    const float* theta = (const float*)d_in[4];
    const float* gnw   = (const float*)d_in[5];
    const float* gnb   = (const float*)d_in[6];
    const float* Wgre  = (const float*)d_in[7];
    const float* Wgim  = (const float*)d_in[8];
    const float* Wore  = (const float*)d_in[9];
    const float* Woim  = (const float*)d_in[10];

    float* ws = (float*)d_ws;
    const size_t P = (size_t)NTOK*HIDDEN;
    float* yre = ws + 0*P;
    float* yim = ws + 1*P;
    float* gre = ws + 2*P;
    float* gim = ws + 3*P;
    float* vv  = ws + 4*P;
    unsigned short* Qbre = (unsigned short*)(ws + 5*P);
    unsigned short* Qbim = Qbre + P;
    unsigned short* Kbre = Qbim + P;
    unsigned short* Kbim = Kbre + P;
    unsigned short* Vtb  = (unsigned short*)(ws + 7*P);
    float* gpw = ws + 7*P + P/2;

    hipLaunchKernelGGL(gpow_kernel, dim3(NHEADS), dim3(SEQ), 0, stream, gpw);
    hipLaunchKernelGGL(proj_kernel, dim3(NTOK/64, NHEADS, 3), dim3(256), 0, stream,
                       X, Wq, Wk, Wv, theta, Qbre, Qbim, Kbre, Kbim, vv);
    hipLaunchKernelGGL(vt_kernel, dim3(NTOK/64, NHEADS), dim3(256), 0, stream, vv, Vtb);
    hipLaunchKernelGGL(attn_kernel, dim3(SEQ/32, BATCH*NHEADS), dim3(64), 0, stream,
                       Qbre, Qbim, Kbre, Kbim, Vtb, gpw, yre, yim);
    hipLaunchKernelGGL(gnorm_kernel, dim3(NTOK*NHEADS/4), dim3(256), 0, stream,
                       yre, yim, gnw, gnb);
    hipLaunchKernelGGL(gswish_kernel, dim3(NTOK/64, HIDDEN/64), dim3(256), 0, stream,
                       X, Wgre, Wgim, gre, gim);
    const int cplx = (out_size >= (int)(2*P)) ? 1 : 0;
    hipLaunchKernelGGL(out_kernel, dim3(NTOK/64, HIDDEN/64), dim3(256), 0, stream,
                       gre, gim, yre, yim, Wore, Woim, (float*)d_out, cplx);
}

// Round 4
// 208.129 us; speedup vs baseline: 4.0399x; 2.3511x over previous
//
#include <hip/hip_runtime.h>
#include <math.h>

#define BATCH  2
#define SEQ    1024
#define HIDDEN 1024
#define NHEADS 8
#define DHEAD  128
#define NTOK   (BATCH*SEQ)
#define GEPS   1e-5f

typedef float f32x16 __attribute__((ext_vector_type(16)));
typedef __bf16 bf16x8 __attribute__((ext_vector_type(8)));
typedef unsigned int u32x4 __attribute__((ext_vector_type(4)));

union Frag { u32x4 u; bf16x8 h; };

__device__ __forceinline__ unsigned short f2bf(float f) {
    unsigned int u = __float_as_uint(f);
    unsigned int r = (u + 0x7FFFu + ((u >> 16) & 1u)) >> 16;
    return (unsigned short)r;
}

// complex swish: z * sigmoid(z)
__device__ __forceinline__ void cswish(float zr, float zi, float& outr, float& outi) {
    const float e = expf(-zr);
    float sg, cg;
    sincosf(zi, &sg, &cg);
    const float wr = fmaf(e, cg, 1.0f);   // 1 + e^{-zr} cos(zi)
    const float wi = -e*sg;               // -e^{-zr} sin(zi)
    const float inv = 1.0f / fmaf(wr, wr, wi*wi);
    outr = (zr*wr + zi*wi)*inv;
    outi = (zi*wr - zr*wi)*inv;
}

// ---------------------------------------------------------------------------
// gamma decay table
// ---------------------------------------------------------------------------
__global__ void gpow_kernel(float* __restrict__ gpow) {
    const int h = blockIdx.x;
    const int k = threadIdx.x;
    const float l = fmaf((float)h, -0.39608410317711170f, -3.46573590279972650f);
    const float gamma = 1.0f - expf(l);
    gpow[h*SEQ + k] = powf(gamma, (float)k);
}

// ---------------------------------------------------------------------------
// per-head projections + RoPE phases -> bf16 Q,K; fp32 V.
// ---------------------------------------------------------------------------
__global__ __launch_bounds__(256) void proj_kernel(
    const float* __restrict__ X,
    const float* __restrict__ Wq, const float* __restrict__ Wk, const float* __restrict__ Wv,
    const float* __restrict__ theta,
    unsigned short* __restrict__ Qbre, unsigned short* __restrict__ Qbim,
    unsigned short* __restrict__ Kbre, unsigned short* __restrict__ Kbim,
    float* __restrict__ vv)
{
    const int tt  = blockIdx.x;
    const int h   = blockIdx.y;
    const int mt  = blockIdx.z;   // 0:q 1:k 2:v
    const int tid = threadIdx.x;

    __shared__ __align__(16) float Xs[64][132];

    for (int i = tid*4; i < 64*128; i += 1024) {
        const int r = i >> 7, c = i & 127;
        *(float4*)&Xs[r][c] = *(const float4*)&X[(size_t)(tt*64 + r)*HIDDEN + h*DHEAD + c];
    }
    __syncthreads();

    const float* W = ((mt == 0) ? Wq : (mt == 1) ? Wk : Wv) + (size_t)h*DHEAD*DHEAD;
    const int tx = tid & 31, ty = tid >> 5;

    float a0[8], a1[8], a2[8], a3[8];
    #pragma unroll
    for (int j = 0; j < 8; ++j) { a0[j]=0.f; a1[j]=0.f; a2[j]=0.f; a3[j]=0.f; }

    #pragma unroll 4
    for (int k = 0; k < DHEAD; ++k) {
        const float4 w = *(const float4*)&W[k*DHEAD + tx*4];
        #pragma unroll
        for (int j = 0; j < 8; ++j) {
            const float x = Xs[ty*8 + j][k];
            a0[j] = fmaf(x, w.x, a0[j]);
            a1[j] = fmaf(x, w.y, a1[j]);
            a2[j] = fmaf(x, w.z, a2[j]);
            a3[j] = fmaf(x, w.w, a3[j]);
        }
    }

    const int d0 = tx*4;
    const float th0 = theta[h*DHEAD + d0 + 0];
    const float th1 = theta[h*DHEAD + d0 + 1];
    const float th2 = theta[h*DHEAD + d0 + 2];
    const float th3 = theta[h*DHEAD + d0 + 3];

    #pragma unroll
    for (int j = 0; j < 8; ++j) {
        const int t = tt*64 + ty*8 + j;
        const size_t g = (size_t)t*HIDDEN + h*DHEAD + d0;
        if (mt == 2) {
            float4 o; o.x=a0[j]; o.y=a1[j]; o.z=a2[j]; o.w=a3[j];
            *(float4*)&vv[g] = o;
        } else {
            const float np1 = (float)((t & (SEQ-1)) + 1);
            float s0,c0,s1,c1,s2,c2,s3,c3;
            sincosf(np1*th0, &s0, &c0);
            sincosf(np1*th1, &s1, &c1);
            sincosf(np1*th2, &s2, &c2);
            sincosf(np1*th3, &s3, &c3);
            float rex = a0[j]*c0, rey = a1[j]*c1, rez = a2[j]*c2, rew = a3[j]*c3;
            float imx, imy, imz, imw;
            if (mt == 0) { imx = a0[j]*s0; imy = a1[j]*s1; imz = a2[j]*s2; imw = a3[j]*s3; }
            else         { imx = -a0[j]*s0; imy = -a1[j]*s1; imz = -a2[j]*s2; imw = -a3[j]*s3; }
            ushort4 o1 = make_ushort4(f2bf(rex), f2bf(rey), f2bf(rez), f2bf(rew));
            ushort4 o2 = make_ushort4(f2bf(imx), f2bf(imy), f2bf(imz), f2bf(imw));
            if (mt == 0) { *(ushort4*)&Qbre[g] = o1; *(ushort4*)&Qbim[g] = o2; }
            else         { *(ushort4*)&Kbre[g] = o1; *(ushort4*)&Kbim[g] = o2; }
        }
    }
}

// ---------------------------------------------------------------------------
// V transpose: vv fp32 [token][h*128+d] -> Vtb bf16 [bh][d][s]
// ---------------------------------------------------------------------------
__global__ __launch_bounds__(256) void vt_kernel(
    const float* __restrict__ vv, unsigned short* __restrict__ Vtb)
{
    const int st  = blockIdx.x;
    const int h   = blockIdx.y;
    const int tid = threadIdx.x;
    const int b  = st >> 4;
    const int s0 = (st & 15)*64;

    __shared__ __align__(16) float Vs[64][132];

    for (int i = tid*4; i < 64*128; i += 1024) {
        const int r = i >> 7, c = i & 127;
        *(float4*)&Vs[r][c] = *(const float4*)&vv[(size_t)(st*64 + r)*HIDDEN + h*DHEAD + c];
    }
    __syncthreads();

    const int d = tid & 127, seg = tid >> 7;
    unsigned short* dst = Vtb + ((size_t)((b*NHEADS + h)*DHEAD + d))*SEQ + s0 + seg*32;
    #pragma unroll
    for (int j = 0; j < 32; j += 2) {
        unsigned int u = (unsigned)f2bf(Vs[seg*32+j][d]) | ((unsigned)f2bf(Vs[seg*32+j+1][d]) << 16);
        *(unsigned int*)(dst + j) = u;
    }
}

// ---------------------------------------------------------------------------
// retention attention, MFMA bf16 (1 wave/block, 32 queries/wave).
// ---------------------------------------------------------------------------
#define CVTPK(dst, a, b) asm("v_cvt_pk_bf16_f32 %0, %1, %2" : "=v"(dst) : "v"(a), "v"(b))
#define SWAP32(x, y)     asm("v_permlane32_swap_b32 %0, %1" : "+v"(x), "+v"(y))

__global__ __launch_bounds__(64) void attn_kernel(
    const unsigned short* __restrict__ Qbre, const unsigned short* __restrict__ Qbim,
    const unsigned short* __restrict__ Kbre, const unsigned short* __restrict__ Kbim,
    const unsigned short* __restrict__ Vtb,  const float* __restrict__ gpow,
    float* __restrict__ yre, float* __restrict__ yim)
{
    const int lane = threadIdx.x;
    const int l31 = lane & 31, hi = lane >> 5;
    const int qt = blockIdx.x;
    const int bh = blockIdx.y;
    const int b = bh >> 3, h = bh & 7;
    const int q0 = qt * 32;
    const size_t bhoff = (size_t)b*SEQ*HIDDEN + h*DHEAD;
    const float* gp = gpow + h*SEQ;

    __shared__ float Yt2[32][133];

    int   crw[16];
    float ginv[16];
    #pragma unroll
    for (int r = 0; r < 16; ++r) {
        const int cr = (r & 3) + 8*(r >> 2) + 4*hi;
        crw[r] = cr;
        ginv[r] = 1.0f / gp[cr];
    }

    Frag Qr[8], Qi[8];
    {
        const unsigned short* qr = Qbre + bhoff + (size_t)(q0 + l31)*HIDDEN + 8*hi;
        const unsigned short* qi = Qbim + bhoff + (size_t)(q0 + l31)*HIDDEN + 8*hi;
        #pragma unroll
        for (int ks = 0; ks < 8; ++ks) {
            Qr[ks].u = *(const u32x4*)(qr + 16*ks);
            Qi[ks].u = *(const u32x4*)(qi + 16*ks);
        }
    }

    f32x16 Yr[4], Yi[4];
    #pragma unroll
    for (int dt = 0; dt < 4; ++dt)
        #pragma unroll
        for (int e = 0; e < 16; ++e) { Yr[dt][e] = 0.f; Yi[dt][e] = 0.f; }

    #pragma unroll 1
    for (int m = 0; m <= qt; ++m) {
        const int kv0 = m*32;

        Frag Kr[8], Ki[8];
        {
            const unsigned short* kr = Kbre + bhoff + (size_t)(kv0 + l31)*HIDDEN + 8*hi;
            const unsigned short* ki = Kbim + bhoff + (size_t)(kv0 + l31)*HIDDEN + 8*hi;
            #pragma unroll
            for (int ks = 0; ks < 8; ++ks) {
                Kr[ks].u = *(const u32x4*)(kr + 16*ks);
                Ki[ks].u = *(const u32x4*)(ki + 16*ks);
            }
        }
        Frag Vf[4][2];
        #pragma unroll
        for (int dt = 0; dt < 4; ++dt)
            #pragma unroll
            for (int ks2 = 0; ks2 < 2; ++ks2)
                Vf[dt][ks2].u = *(const u32x4*)(Vtb + ((size_t)(bh*DHEAD + dt*32 + l31))*SEQ
                                                + kv0 + 16*ks2 + 8*hi);

        const int  base = 32*(qt - m) + l31;
        const float g1  = gp[base];

        f32x16 SR, SI;
        #pragma unroll
        for (int e = 0; e < 16; ++e) { SR[e] = 0.f; SI[e] = 0.f; }
        #pragma unroll
        for (int ks = 0; ks < 8; ++ks) {
            Frag Qin;
            #pragma unroll
            for (int e = 0; e < 4; ++e) Qin.u[e] = Qi[ks].u[e] ^ 0x80008000u;
            SR = __builtin_amdgcn_mfma_f32_32x32x16_bf16(Kr[ks].h, Qr[ks].h, SR, 0, 0, 0);
            SI = __builtin_amdgcn_mfma_f32_32x32x16_bf16(Kr[ks].h, Qi[ks].h, SI, 0, 0, 0);
            SR = __builtin_amdgcn_mfma_f32_32x32x16_bf16(Ki[ks].h, Qin.h, SR, 0, 0, 0);
            SI = __builtin_amdgcn_mfma_f32_32x32x16_bf16(Ki[ks].h, Qr[ks].h, SI, 0, 0, 0);
        }

        float pr[16], pi[16];
        #pragma unroll
        for (int r = 0; r < 16; ++r) {
            const float w = (base >= crw[r]) ? g1*ginv[r] : 0.0f;
            pr[r] = SR[r]*w;
            pi[r] = SI[r]*w;
        }

        Frag PR[2], PI[2];
        #pragma unroll
        for (int ks2 = 0; ks2 < 2; ++ks2) {
            const int o = ks2*8;
            unsigned int a0, b0, a1, b1;
            CVTPK(a0, pr[o+0], pr[o+1]);
            CVTPK(b0, pr[o+4], pr[o+5]);
            SWAP32(a0, b0);
            CVTPK(a1, pr[o+2], pr[o+3]);
            CVTPK(b1, pr[o+6], pr[o+7]);
            SWAP32(a1, b1);
            PR[ks2].u[0] = a0; PR[ks2].u[1] = a1; PR[ks2].u[2] = b0; PR[ks2].u[3] = b1;
            CVTPK(a0, pi[o+0], pi[o+1]);
            CVTPK(b0, pi[o+4], pi[o+5]);
            SWAP32(a0, b0);
            CVTPK(a1, pi[o+2], pi[o+3]);
            CVTPK(b1, pi[o+6], pi[o+7]);
            SWAP32(a1, b1);
            PI[ks2].u[0] = a0; PI[ks2].u[1] = a1; PI[ks2].u[2] = b0; PI[ks2].u[3] = b1;
        }

        #pragma unroll
        for (int dt = 0; dt < 4; ++dt) {
            Yr[dt] = __builtin_amdgcn_mfma_f32_32x32x16_bf16(Vf[dt][0].h, PR[0].h, Yr[dt], 0, 0, 0);
            Yr[dt] = __builtin_amdgcn_mfma_f32_32x32x16_bf16(Vf[dt][1].h, PR[1].h, Yr[dt], 0, 0, 0);
            Yi[dt] = __builtin_amdgcn_mfma_f32_32x32x16_bf16(Vf[dt][0].h, PI[0].h, Yi[dt], 0, 0, 0);
            Yi[dt] = __builtin_amdgcn_mfma_f32_32x32x16_bf16(Vf[dt][1].h, PI[1].h, Yi[dt], 0, 0, 0);
        }
    }

    #pragma unroll
    for (int part = 0; part < 2; ++part) {
        __syncthreads();
        #pragma unroll
        for (int dt = 0; dt < 4; ++dt)
            #pragma unroll
            for (int r = 0; r < 16; ++r)
                Yt2[l31][dt*32 + crw[r]] = part ? Yi[dt][r] : Yr[dt][r];
        __syncthreads();
        const int t = lane >> 1, half = lane & 1;
        float* dst = (part ? yim : yre) + bhoff + (size_t)(q0 + t)*HIDDEN + 64*half;
        #pragma unroll
        for (int j = 0; j < 16; ++j) {
            float4 o;
            o.x = Yt2[t][64*half + 4*j + 0];
            o.y = Yt2[t][64*half + 4*j + 1];
            o.z = Yt2[t][64*half + 4*j + 2];
            o.w = Yt2[t][64*half + 4*j + 3];
            *(float4*)(dst + 4*j) = o;
        }
    }
}

// ---------------------------------------------------------------------------
// X fp32 -> bf16 pack
// ---------------------------------------------------------------------------
__global__ __launch_bounds__(256) void xprep_kernel(
    const float* __restrict__ X, unsigned short* __restrict__ Xb)
{
    const size_t i = ((size_t)blockIdx.x*256 + threadIdx.x)*8;
    const float4 a = *(const float4*)&X[i];
    const float4 b = *(const float4*)&X[i+4];
    __align__(16) unsigned short t[8] = { f2bf(a.x), f2bf(a.y), f2bf(a.z), f2bf(a.w),
                                          f2bf(b.x), f2bf(b.y), f2bf(b.z), f2bf(b.w) };
    *(u32x4*)&Xb[i] = *(u32x4*)t;
}

// ---------------------------------------------------------------------------
// Bgt[n][k] = (n<1024 ? Wgre : Wgim)[k][n&1023]  -- bf16, [2048][1024]
// ---------------------------------------------------------------------------
__global__ __launch_bounds__(256) void wprep_g_kernel(
    const float* __restrict__ Wgre, const float* __restrict__ Wgim,
    unsigned short* __restrict__ Bgt)
{
    const int n0 = blockIdx.x*64, k0 = blockIdx.y*64;
    const float* src = (n0 < HIDDEN) ? Wgre : Wgim;
    const int nc = n0 & (HIDDEN-1);
    __shared__ float Ws[64][65];
    const int tid = threadIdx.x;
    #pragma unroll
    for (int it = 0; it < 4; ++it) {
        const int r = (tid >> 4) + it*16, c = (tid & 15)*4;
        *(float4*)&Ws[r][c] = *(const float4*)&src[(size_t)(k0 + r)*HIDDEN + nc + c];
    }
    __syncthreads();
    const int nl = tid >> 2, seg = (tid & 3)*16;
    __align__(16) unsigned short t[16];
    #pragma unroll
    for (int j = 0; j < 16; ++j) t[j] = f2bf(Ws[seg + j][nl]);
    u32x4* d = (u32x4*)&Bgt[(size_t)(n0 + nl)*HIDDEN + k0 + seg];
    d[0] = ((u32x4*)t)[0];
    d[1] = ((u32x4*)t)[1];
}

// ---------------------------------------------------------------------------
// Bot[n][k] (bf16, [1024][2048]):
//   imMode=0: k<1024 ?  Wore[k][n] : -Woim[k-1024][n]   (real-part weights)
//   imMode=1: k<1024 ?  Woim[k][n] :  Wore[k-1024][n]   (imag-part weights)
// ---------------------------------------------------------------------------
__global__ __launch_bounds__(256) void wprep_o_kernel(
    const float* __restrict__ Wore, const float* __restrict__ Woim,
    unsigned short* __restrict__ Bot, const int imMode)
{
    const int n0 = blockIdx.x*64, k0 = blockIdx.y*64;
    const float* src;
    float sign = 1.0f;
    if (!imMode) { if (k0 < HIDDEN) src = Wore; else { src = Woim; sign = -1.0f; } }
    else         { src = (k0 < HIDDEN) ? Woim : Wore; }
    const int kc = k0 & (HIDDEN-1);
    __shared__ float Ws[64][65];
    const int tid = threadIdx.x;
    #pragma unroll
    for (int it = 0; it < 4; ++it) {
        const int r = (tid >> 4) + it*16, c = (tid & 15)*4;
        const float4 v = *(const float4*)&src[(size_t)(kc + r)*HIDDEN + n0 + c];
        Ws[r][c+0] = v.x*sign; Ws[r][c+1] = v.y*sign; Ws[r][c+2] = v.z*sign; Ws[r][c+3] = v.w*sign;
    }
    __syncthreads();
    const int nl = tid >> 2, seg = (tid & 3)*16;
    __align__(16) unsigned short t[16];
    #pragma unroll
    for (int j = 0; j < 16; ++j) t[j] = f2bf(Ws[seg + j][nl]);
    u32x4* d = (u32x4*)&Bot[(size_t)(n0 + nl)*(2*HIDDEN) + k0 + seg];
    d[0] = ((u32x4*)t)[0];
    d[1] = ((u32x4*)t)[1];
}

// ---------------------------------------------------------------------------
// generic bf16 MFMA GEMM: C[M][N] = A[M][K] @ Bt[N][K]^T
// 128x128 tile, BK=64, 4 waves (2x2 of 32x32x16 frags each).
// mode 0: plain fp32 store; mode 1/2: interleaved complex re/im store.
// ---------------------------------------------------------------------------
__global__ __launch_bounds__(256) void gemm_bf16_kernel(
    const unsigned short* __restrict__ A,
    const unsigned short* __restrict__ Bt,
    float* __restrict__ C,
    const int K, const int N, const int mode)
{
    __shared__ __align__(16) unsigned short As[128][72];
    __shared__ __align__(16) unsigned short Bs[128][72];

    const int tid = threadIdx.x;
    const int mb = blockIdx.x, nb = blockIdx.y;
    const int lane = tid & 63, w = tid >> 6;
    const int l31 = lane & 31, hi = lane >> 5;
    const int wm = (w >> 1) * 64, wn = (w & 1) * 64;

    const int srow = tid >> 2;          // 0..63
    const int sseg = (tid & 3) * 16;    // 0,16,32,48 (full 64-col tile)

    const unsigned short* ga = A  + (size_t)(mb*128 + srow)*K + sseg;
    const unsigned short* gb = Bt + (size_t)(nb*128 + srow)*K + sseg;

    f32x16 acc00, acc01, acc10, acc11;
    #pragma unroll
    for (int e = 0; e < 16; ++e) { acc00[e]=0.f; acc01[e]=0.f; acc10[e]=0.f; acc11[e]=0.f; }

    u32x4 ra0 = *(const u32x4*)(ga);
    u32x4 ra1 = *(const u32x4*)(ga + 8);
    u32x4 ra2 = *(const u32x4*)(ga + (size_t)64*K);
    u32x4 ra3 = *(const u32x4*)(ga + (size_t)64*K + 8);
    u32x4 rb0 = *(const u32x4*)(gb);
    u32x4 rb1 = *(const u32x4*)(gb + 8);
    u32x4 rb2 = *(const u32x4*)(gb + (size_t)64*K);
    u32x4 rb3 = *(const u32x4*)(gb + (size_t)64*K + 8);

    for (int kk = 0; kk < K; kk += 64) {
        __syncthreads();
        *(u32x4*)&As[srow][sseg]          = ra0;
        *(u32x4*)&As[srow][sseg + 8]      = ra1;
        *(u32x4*)&As[srow + 64][sseg]     = ra2;
        *(u32x4*)&As[srow + 64][sseg + 8] = ra3;
        *(u32x4*)&Bs[srow][sseg]          = rb0;
        *(u32x4*)&Bs[srow][sseg + 8]      = rb1;
        *(u32x4*)&Bs[srow + 64][sseg]     = rb2;
        *(u32x4*)&Bs[srow + 64][sseg + 8] = rb3;
        if (kk + 64 < K) {
            const int o = kk + 64;
            ra0 = *(const u32x4*)(ga + o);
            ra1 = *(const u32x4*)(ga + o + 8);
            ra2 = *(const u32x4*)(ga + (size_t)64*K + o);
            ra3 = *(const u32x4*)(ga + (size_t)64*K + o + 8);
            rb0 = *(const u32x4*)(gb + o);
            rb1 = *(const u32x4*)(gb + o + 8);
            rb2 = *(const u32x4*)(gb + (size_t)64*K + o);
            rb3 = *(const u32x4*)(gb + (size_t)64*K + o + 8);
        }
        __syncthreads();
        #pragma unroll
        for (int ks = 0; ks < 4; ++ks) {
            Frag a0, a1, b0, b1;
            a0.u = *(const u32x4*)&As[wm + l31     ][ks*16 + hi*8];
            a1.u = *(const u32x4*)&As[wm + l31 + 32][ks*16 + hi*8];
            b0.u = *(const u32x4*)&Bs[wn + l31     ][ks*16 + hi*8];
            b1.u = *(const u32x4*)&Bs[wn + l31 + 32][ks*16 + hi*8];
            acc00 = __builtin_amdgcn_mfma_f32_32x32x16_bf16(a0.h, b0.h, acc00, 0, 0, 0);
            acc01 = __builtin_amdgcn_mfma_f32_32x32x16_bf16(a0.h, b1.h, acc01, 0, 0, 0);
            acc10 = __builtin_amdgcn_mfma_f32_32x32x16_bf16(a1.h, b0.h, acc10, 0, 0, 0);
            acc11 = __builtin_amdgcn_mfma_f32_32x32x16_bf16(a1.h, b1.h, acc11, 0, 0, 0);
        }
    }

    const int cb = nb*128 + wn + l31;
    #pragma unroll
    for (int i = 0; i < 2; ++i) {
        const f32x16& c0 = i ? acc10 : acc00;
        const f32x16& c1 = i ? acc11 : acc01;
        #pragma unroll
        for (int r = 0; r < 16; ++r) {
            const int row = mb*128 + wm + 32*i + (r & 3) + 8*(r >> 2) + 4*hi;
            if (mode == 0) {
                float* cr = C + (size_t)row*N + cb;
                cr[0]  = c0[r];
                cr[32] = c1[r];
            } else {
                float* cr = C + ((size_t)row*N + cb)*2 + (mode - 1);
                cr[0]  = c0[r];
                cr[64] = c1[r];
            }
        }
    }
}

// ---------------------------------------------------------------------------
// fused: group-norm(Y) + swish(G) + add -> Aout bf16 [2048][2048] (Zr | Zi)
// ---------------------------------------------------------------------------
__global__ __launch_bounds__(256) void znorm_kernel(
    const float* __restrict__ yre, const float* __restrict__ yim,
    const float* __restrict__ Graw,
    const float* __restrict__ w, const float* __restrict__ bbv,
    unsigned short* __restrict__ Aout)
{
    const int row  = blockIdx.x;
    const int wv   = threadIdx.x >> 6;
    const int lane = threadIdx.x & 63;

    #pragma unroll
    for (int gi = 0; gi < 2; ++gi) {
        const int h = wv*2 + gi;
        const size_t base = (size_t)row*HIDDEN + h*DHEAD;

        const float r0 = yre[base + lane];
        const float r1 = yre[base + lane + 64];
        const float i0 = yim[base + lane];
        const float i1 = yim[base + lane + 64];

        float sr = r0 + r1, si = i0 + i1;
        #pragma unroll
        for (int off = 32; off > 0; off >>= 1) {
            sr += __shfl_xor(sr, off);
            si += __shfl_xor(si, off);
        }
        const float mr = sr * (1.0f/128.0f), mi = si * (1.0f/128.0f);
        const float d0r = r0 - mr, d1r = r1 - mr, d0i = i0 - mi, d1i = i1 - mi;
        float vs = d0r*d0r + d0i*d0i + d1r*d1r + d1i*d1i;
        #pragma unroll
        for (int off = 32; off > 0; off >>= 1) vs += __shfl_xor(vs, off);
        const float scale = 1.0f / sqrtf(vs * (1.0f/127.0f) + GEPS);

        const float w0 = w[h*DHEAD + lane],   w1 = w[h*DHEAD + lane + 64];
        const float b0 = bbv[h*DHEAD + lane], b1 = bbv[h*DHEAD + lane + 64];
        const float zr0 = fmaf(d0r*scale, w0, b0);
        const float zr1 = fmaf(d1r*scale, w1, b1);
        const float zi0 = d0i*scale*w0;
        const float zi1 = d1i*scale*w1;

        const int col = h*DHEAD + lane;
        const size_t gbase = (size_t)row*(2*HIDDEN);
        const float gr0 = Graw[gbase + col];
        const float gr1 = Graw[gbase + col + 64];
        const float gi0 = Graw[gbase + HIDDEN + col];
        const float gi1 = Graw[gbase + HIDDEN + col + 64];

        float s0r, s0i, s1r, s1i;
        cswish(gr0, gi0, s0r, s0i);
        cswish(gr1, gi1, s1r, s1i);

        Aout[gbase + col]               = f2bf(s0r + zr0);
        Aout[gbase + col + 64]          = f2bf(s1r + zr1);
        Aout[gbase + HIDDEN + col]      = f2bf(s0i + zi0);
        Aout[gbase + HIDDEN + col + 64] = f2bf(s1i + zi1);
    }
}

// ---------------------------------------------------------------------------
extern "C" void kernel_launch(void* const* d_in, const int* in_sizes, int n_in,
                              void* d_out, int out_size, void* d_ws, size_t ws_size,
                              hipStream_t stream)
{
    (void)in_sizes; (void)n_in; (void)ws_size;

    const float* X     = (const float*)d_in[0];
    const float* Wq    = (const float*)d_in[1];
    const float* Wk    = (const float*)d_in[2];
    const float* Wv    = (const float*)d_in[3];
    const float* theta = (const float*)d_in[4];
    const float* gnw   = (const float*)d_in[5];
    const float* gnb   = (const float*)d_in[6];
    const float* Wgre  = (const float*)d_in[7];
    const float* Wgim  = (const float*)d_in[8];
    const float* Wore  = (const float*)d_in[9];
    const float* Woim  = (const float*)d_in[10];

    float* ws = (float*)d_ws;
    const size_t P = (size_t)NTOK*HIDDEN;          // 2M elements

    float* yre = ws;                               // [0, P)
    float* yim = ws + P;                           // [P, 2P)
    unsigned short* Qbre = (unsigned short*)(ws + 2*P);  // [2P,4P) as 4 x P ushort
    unsigned short* Qbim = Qbre + P;
    unsigned short* Kbre = Qbim + P;
    unsigned short* Kbim = Kbre + P;
    float* Graw = ws + 2*P;                        // alias Q/K (dead after attn), [2P,4P)
    float* vv   = ws + 4*P;                        // [4P,5P)
    unsigned short* Aout = (unsigned short*)(ws + 4*P);  // alias vv (dead after vt)
    unsigned short* Vtb  = (unsigned short*)(ws + 5*P);  // [5P,5.5P)
    unsigned short* Bot  = Vtb;                    // alias Vtb (dead after attn)
    unsigned short* Xb   = (unsigned short*)(ws + 5*P) + P;      // [5.5P,6P)
    unsigned short* Bgt  = (unsigned short*)(ws + 6*P);          // [6P,6.5P)
    unsigned short* Boti = (unsigned short*)(ws + 6*P) + P;      // [6.5P,7P) cplx only
    float* gpw = ws + 7*P;

    const int cplx = (out_size >= (int)(2*P)) ? 1 : 0;

    hipLaunchKernelGGL(gpow_kernel, dim3(NHEADS), dim3(SEQ), 0, stream, gpw);
    hipLaunchKernelGGL(proj_kernel, dim3(NTOK/64, NHEADS, 3), dim3(256), 0, stream,
                       X, Wq, Wk, Wv, theta, Qbre, Qbim, Kbre, Kbim, vv);
    hipLaunchKernelGGL(vt_kernel, dim3(NTOK/64, NHEADS), dim3(256), 0, stream, vv, Vtb);
    hipLaunchKernelGGL(attn_kernel, dim3(SEQ/32, BATCH*NHEADS), dim3(64), 0, stream,
                       Qbre, Qbim, Kbre, Kbim, Vtb, gpw, yre, yim);

    // gating path (after attn: Graw aliases Q/K)
    hipLaunchKernelGGL(xprep_kernel, dim3(NTOK*HIDDEN/(256*8)), dim3(256), 0, stream, X, Xb);
    hipLaunchKernelGGL(wprep_g_kernel, dim3(2*HIDDEN/64, HIDDEN/64), dim3(256), 0, stream,
                       Wgre, Wgim, Bgt);
    hipLaunchKernelGGL(gemm_bf16_kernel, dim3(NTOK/128, 2*HIDDEN/128), dim3(256), 0, stream,
                       Xb, Bgt, Graw, HIDDEN, 2*HIDDEN, 0);

    // fused norm + swish + add -> bf16 A
    hipLaunchKernelGGL(znorm_kernel, dim3(NTOK), dim3(256), 0, stream,
                       yre, yim, Graw, gnw, gnb, Aout);

    // output projection
    hipLaunchKernelGGL(wprep_o_kernel, dim3(HIDDEN/64, 2*HIDDEN/64), dim3(256), 0, stream,
                       Wore, Woim, Bot, 0);
    if (!cplx) {
        hipLaunchKernelGGL(gemm_bf16_kernel, dim3(NTOK/128, HIDDEN/128), dim3(256), 0, stream,
                           Aout, Bot, (float*)d_out, 2*HIDDEN, HIDDEN, 0);
    } else {
        hipLaunchKernelGGL(wprep_o_kernel, dim3(HIDDEN/64, 2*HIDDEN/64), dim3(256), 0, stream,
                           Wore, Woim, Boti, 1);
        hipLaunchKernelGGL(gemm_bf16_kernel, dim3(NTOK/128, HIDDEN/128), dim3(256), 0, stream,
                           Aout, Bot, (float*)d_out, 2*HIDDEN, HIDDEN, 1);
        hipLaunchKernelGGL(gemm_bf16_kernel, dim3(NTOK/128, HIDDEN/128), dim3(256), 0, stream,
                           Aout, Boti, (float*)d_out, 2*HIDDEN, HIDDEN, 2);
    }
}

// Round 5
// 159.006 us; speedup vs baseline: 5.2879x; 1.3089x over previous
//
#include <hip/hip_runtime.h>
#include <math.h>

#define BATCH  2
#define SEQ    1024
#define HIDDEN 1024
#define NHEADS 8
#define DHEAD  128
#define NTOK   (BATCH*SEQ)
#define GEPS   1e-5f

typedef float f32x16 __attribute__((ext_vector_type(16)));
typedef __bf16 bf16x8 __attribute__((ext_vector_type(8)));
typedef unsigned int u32x4 __attribute__((ext_vector_type(4)));

union Frag { u32x4 u; bf16x8 h; };

__device__ __forceinline__ unsigned short f2bf(float f) {
    unsigned int u = __float_as_uint(f);
    unsigned int r = (u + 0x7FFFu + ((u >> 16) & 1u)) >> 16;
    return (unsigned short)r;
}

// complex swish: z * sigmoid(z)
__device__ __forceinline__ void cswish(float zr, float zi, float& outr, float& outi) {
    const float e = expf(-zr);
    float sg, cg;
    sincosf(zi, &sg, &cg);
    const float wr = fmaf(e, cg, 1.0f);   // 1 + e^{-zr} cos(zi)
    const float wi = -e*sg;               // -e^{-zr} sin(zi)
    const float inv = 1.0f / fmaf(wr, wr, wi*wi);
    outr = (zr*wr + zi*wi)*inv;
    outi = (zi*wr - zr*wi)*inv;
}

// ---------------------------------------------------------------------------
// gamma decay table
// ---------------------------------------------------------------------------
__global__ void gpow_kernel(float* __restrict__ gpow) {
    const int h = blockIdx.x;
    const int k = threadIdx.x;
    const float l = fmaf((float)h, -0.39608410317711170f, -3.46573590279972650f);
    const float gamma = 1.0f - expf(l);
    gpow[h*SEQ + k] = powf(gamma, (float)k);
}

// ---------------------------------------------------------------------------
// per-head projections + RoPE phases -> bf16 Q,K; fp32 V.
// ---------------------------------------------------------------------------
__global__ __launch_bounds__(256) void proj_kernel(
    const float* __restrict__ X,
    const float* __restrict__ Wq, const float* __restrict__ Wk, const float* __restrict__ Wv,
    const float* __restrict__ theta,
    unsigned short* __restrict__ Qbre, unsigned short* __restrict__ Qbim,
    unsigned short* __restrict__ Kbre, unsigned short* __restrict__ Kbim,
    float* __restrict__ vv)
{
    const int tt  = blockIdx.x;
    const int h   = blockIdx.y;
    const int mt  = blockIdx.z;   // 0:q 1:k 2:v
    const int tid = threadIdx.x;

    __shared__ __align__(16) float Xs[64][132];

    for (int i = tid*4; i < 64*128; i += 1024) {
        const int r = i >> 7, c = i & 127;
        *(float4*)&Xs[r][c] = *(const float4*)&X[(size_t)(tt*64 + r)*HIDDEN + h*DHEAD + c];
    }
    __syncthreads();

    const float* W = ((mt == 0) ? Wq : (mt == 1) ? Wk : Wv) + (size_t)h*DHEAD*DHEAD;
    const int tx = tid & 31, ty = tid >> 5;

    float a0[8], a1[8], a2[8], a3[8];
    #pragma unroll
    for (int j = 0; j < 8; ++j) { a0[j]=0.f; a1[j]=0.f; a2[j]=0.f; a3[j]=0.f; }

    #pragma unroll 4
    for (int k = 0; k < DHEAD; ++k) {
        const float4 w = *(const float4*)&W[k*DHEAD + tx*4];
        #pragma unroll
        for (int j = 0; j < 8; ++j) {
            const float x = Xs[ty*8 + j][k];
            a0[j] = fmaf(x, w.x, a0[j]);
            a1[j] = fmaf(x, w.y, a1[j]);
            a2[j] = fmaf(x, w.z, a2[j]);
            a3[j] = fmaf(x, w.w, a3[j]);
        }
    }

    const int d0 = tx*4;
    const float th0 = theta[h*DHEAD + d0 + 0];
    const float th1 = theta[h*DHEAD + d0 + 1];
    const float th2 = theta[h*DHEAD + d0 + 2];
    const float th3 = theta[h*DHEAD + d0 + 3];

    #pragma unroll
    for (int j = 0; j < 8; ++j) {
        const int t = tt*64 + ty*8 + j;
        const size_t g = (size_t)t*HIDDEN + h*DHEAD + d0;
        if (mt == 2) {
            float4 o; o.x=a0[j]; o.y=a1[j]; o.z=a2[j]; o.w=a3[j];
            *(float4*)&vv[g] = o;
        } else {
            const float np1 = (float)((t & (SEQ-1)) + 1);
            float s0,c0,s1,c1,s2,c2,s3,c3;
            sincosf(np1*th0, &s0, &c0);
            sincosf(np1*th1, &s1, &c1);
            sincosf(np1*th2, &s2, &c2);
            sincosf(np1*th3, &s3, &c3);
            float rex = a0[j]*c0, rey = a1[j]*c1, rez = a2[j]*c2, rew = a3[j]*c3;
            float imx, imy, imz, imw;
            if (mt == 0) { imx = a0[j]*s0; imy = a1[j]*s1; imz = a2[j]*s2; imw = a3[j]*s3; }
            else         { imx = -a0[j]*s0; imy = -a1[j]*s1; imz = -a2[j]*s2; imw = -a3[j]*s3; }
            ushort4 o1 = make_ushort4(f2bf(rex), f2bf(rey), f2bf(rez), f2bf(rew));
            ushort4 o2 = make_ushort4(f2bf(imx), f2bf(imy), f2bf(imz), f2bf(imw));
            if (mt == 0) { *(ushort4*)&Qbre[g] = o1; *(ushort4*)&Qbim[g] = o2; }
            else         { *(ushort4*)&Kbre[g] = o1; *(ushort4*)&Kbim[g] = o2; }
        }
    }
}

// ---------------------------------------------------------------------------
// V transpose: vv fp32 [token][h*128+d] -> Vtb bf16 [bh][d][s]
// ---------------------------------------------------------------------------
__global__ __launch_bounds__(256) void vt_kernel(
    const float* __restrict__ vv, unsigned short* __restrict__ Vtb)
{
    const int st  = blockIdx.x;
    const int h   = blockIdx.y;
    const int tid = threadIdx.x;
    const int b  = st >> 4;
    const int s0 = (st & 15)*64;

    __shared__ __align__(16) float Vs[64][132];

    for (int i = tid*4; i < 64*128; i += 1024) {
        const int r = i >> 7, c = i & 127;
        *(float4*)&Vs[r][c] = *(const float4*)&vv[(size_t)(st*64 + r)*HIDDEN + h*DHEAD + c];
    }
    __syncthreads();

    const int d = tid & 127, seg = tid >> 7;
    unsigned short* dst = Vtb + ((size_t)((b*NHEADS + h)*DHEAD + d))*SEQ + s0 + seg*32;
    #pragma unroll
    for (int j = 0; j < 32; j += 2) {
        unsigned int u = (unsigned)f2bf(Vs[seg*32+j][d]) | ((unsigned)f2bf(Vs[seg*32+j+1][d]) << 16);
        *(unsigned int*)(dst + j) = u;
    }
}

// ---------------------------------------------------------------------------
// retention attention, MFMA bf16.
// 2 waves per block split the causal m-range; LDS combine; XCD-chunked grid.
// ---------------------------------------------------------------------------
#define CVTPK(dst, a, b) asm("v_cvt_pk_bf16_f32 %0, %1, %2" : "=v"(dst) : "v"(a), "v"(b))
#define SWAP32(x, y)     asm("v_permlane32_swap_b32 %0, %1" : "+v"(x), "+v"(y))

__global__ __launch_bounds__(128) void attn_kernel(
    const unsigned short* __restrict__ Qbre, const unsigned short* __restrict__ Qbim,
    const unsigned short* __restrict__ Kbre, const unsigned short* __restrict__ Kbim,
    const unsigned short* __restrict__ Vtb,  const float* __restrict__ gpow,
    float* __restrict__ yre, float* __restrict__ yim)
{
    const int tid  = threadIdx.x;
    const int lane = tid & 63;
    const int wv   = tid >> 6;
    const int l31 = lane & 31, hi = (lane >> 5) & 1;

    // XCD-chunked decode: id%8 = bh>>1  (each XCD owns 2 (b,h) pairs)
    const int id = blockIdx.x;
    const int bh = ((id & 7) << 1) | ((id >> 3) & 1);
    const int qt = id >> 4;

    const int b = bh >> 3, h = bh & 7;
    const int q0 = qt * 32;
    const size_t bhoff = (size_t)b*SEQ*HIDDEN + h*DHEAD;
    const float* gp = gpow + h*SEQ;

    __shared__ float Yt2[32][133];

    int   crw[16];
    float ginv[16];
    #pragma unroll
    for (int r = 0; r < 16; ++r) {
        const int cr = (r & 3) + 8*(r >> 2) + 4*hi;
        crw[r] = cr;
        ginv[r] = 1.0f / gp[cr];
    }

    Frag Qr[8], Qi[8];
    {
        const unsigned short* qr = Qbre + bhoff + (size_t)(q0 + l31)*HIDDEN + 8*hi;
        const unsigned short* qi = Qbim + bhoff + (size_t)(q0 + l31)*HIDDEN + 8*hi;
        #pragma unroll
        for (int ks = 0; ks < 8; ++ks) {
            Qr[ks].u = *(const u32x4*)(qr + 16*ks);
            Qi[ks].u = *(const u32x4*)(qi + 16*ks);
        }
    }

    f32x16 Yr[4], Yi[4];
    #pragma unroll
    for (int dt = 0; dt < 4; ++dt)
        #pragma unroll
        for (int e = 0; e < 16; ++e) { Yr[dt][e] = 0.f; Yi[dt][e] = 0.f; }

    // m-range split across the 2 waves
    const int nm   = qt + 1;
    const int half = (nm + 1) >> 1;
    const int mlo  = wv ? half : 0;
    const int mhi  = wv ? nm   : half;

    #pragma unroll 1
    for (int m = mlo; m < mhi; ++m) {
        const int kv0 = m*32;

        Frag Kr[8], Ki[8];
        {
            const unsigned short* kr = Kbre + bhoff + (size_t)(kv0 + l31)*HIDDEN + 8*hi;
            const unsigned short* ki = Kbim + bhoff + (size_t)(kv0 + l31)*HIDDEN + 8*hi;
            #pragma unroll
            for (int ks = 0; ks < 8; ++ks) {
                Kr[ks].u = *(const u32x4*)(kr + 16*ks);
                Ki[ks].u = *(const u32x4*)(ki + 16*ks);
            }
        }
        Frag Vf[4][2];
        #pragma unroll
        for (int dt = 0; dt < 4; ++dt)
            #pragma unroll
            for (int ks2 = 0; ks2 < 2; ++ks2)
                Vf[dt][ks2].u = *(const u32x4*)(Vtb + ((size_t)(bh*DHEAD + dt*32 + l31))*SEQ
                                                + kv0 + 16*ks2 + 8*hi);

        const int  base = 32*(qt - m) + l31;
        const float g1  = gp[base];

        f32x16 SR, SI;
        #pragma unroll
        for (int e = 0; e < 16; ++e) { SR[e] = 0.f; SI[e] = 0.f; }
        #pragma unroll
        for (int ks = 0; ks < 8; ++ks) {
            Frag Qin;
            #pragma unroll
            for (int e = 0; e < 4; ++e) Qin.u[e] = Qi[ks].u[e] ^ 0x80008000u;
            SR = __builtin_amdgcn_mfma_f32_32x32x16_bf16(Kr[ks].h, Qr[ks].h, SR, 0, 0, 0);
            SI = __builtin_amdgcn_mfma_f32_32x32x16_bf16(Kr[ks].h, Qi[ks].h, SI, 0, 0, 0);
            SR = __builtin_amdgcn_mfma_f32_32x32x16_bf16(Ki[ks].h, Qin.h, SR, 0, 0, 0);
            SI = __builtin_amdgcn_mfma_f32_32x32x16_bf16(Ki[ks].h, Qr[ks].h, SI, 0, 0, 0);
        }

        float pr[16], pi[16];
        #pragma unroll
        for (int r = 0; r < 16; ++r) {
            const float w = (base >= crw[r]) ? g1*ginv[r] : 0.0f;
            pr[r] = SR[r]*w;
            pi[r] = SI[r]*w;
        }

        Frag PR[2], PI[2];
        #pragma unroll
        for (int ks2 = 0; ks2 < 2; ++ks2) {
            const int o = ks2*8;
            unsigned int a0, b0, a1, b1;
            CVTPK(a0, pr[o+0], pr[o+1]);
            CVTPK(b0, pr[o+4], pr[o+5]);
            SWAP32(a0, b0);
            CVTPK(a1, pr[o+2], pr[o+3]);
            CVTPK(b1, pr[o+6], pr[o+7]);
            SWAP32(a1, b1);
            PR[ks2].u[0] = a0; PR[ks2].u[1] = a1; PR[ks2].u[2] = b0; PR[ks2].u[3] = b1;
            CVTPK(a0, pi[o+0], pi[o+1]);
            CVTPK(b0, pi[o+4], pi[o+5]);
            SWAP32(a0, b0);
            CVTPK(a1, pi[o+2], pi[o+3]);
            CVTPK(b1, pi[o+6], pi[o+7]);
            SWAP32(a1, b1);
            PI[ks2].u[0] = a0; PI[ks2].u[1] = a1; PI[ks2].u[2] = b0; PI[ks2].u[3] = b1;
        }

        #pragma unroll
        for (int dt = 0; dt < 4; ++dt) {
            Yr[dt] = __builtin_amdgcn_mfma_f32_32x32x16_bf16(Vf[dt][0].h, PR[0].h, Yr[dt], 0, 0, 0);
            Yr[dt] = __builtin_amdgcn_mfma_f32_32x32x16_bf16(Vf[dt][1].h, PR[1].h, Yr[dt], 0, 0, 0);
            Yi[dt] = __builtin_amdgcn_mfma_f32_32x32x16_bf16(Vf[dt][0].h, PI[0].h, Yi[dt], 0, 0, 0);
            Yi[dt] = __builtin_amdgcn_mfma_f32_32x32x16_bf16(Vf[dt][1].h, PI[1].h, Yi[dt], 0, 0, 0);
        }
    }

    // combine the 2 waves' partials + transposed store via LDS
    #pragma unroll
    for (int part = 0; part < 2; ++part) {
        __syncthreads();
        if (wv == 0) {
            #pragma unroll
            for (int dt = 0; dt < 4; ++dt)
                #pragma unroll
                for (int r = 0; r < 16; ++r)
                    Yt2[l31][dt*32 + crw[r]] = part ? Yi[dt][r] : Yr[dt][r];
        }
        __syncthreads();
        if (wv == 1) {
            #pragma unroll
            for (int dt = 0; dt < 4; ++dt)
                #pragma unroll
                for (int r = 0; r < 16; ++r)
                    Yt2[l31][dt*32 + crw[r]] += part ? Yi[dt][r] : Yr[dt][r];
        }
        __syncthreads();
        const int t = tid >> 2, q4 = tid & 3;
        float* dst = (part ? yim : yre) + bhoff + (size_t)(q0 + t)*HIDDEN + q4*32;
        #pragma unroll
        for (int j = 0; j < 8; ++j) {
            float4 o;
            o.x = Yt2[t][q4*32 + 4*j + 0];
            o.y = Yt2[t][q4*32 + 4*j + 1];
            o.z = Yt2[t][q4*32 + 4*j + 2];
            o.w = Yt2[t][q4*32 + 4*j + 3];
            *(float4*)(dst + 4*j) = o;
        }
    }
}

// ---------------------------------------------------------------------------
// X fp32 -> bf16 pack
// ---------------------------------------------------------------------------
__global__ __launch_bounds__(256) void xprep_kernel(
    const float* __restrict__ X, unsigned short* __restrict__ Xb)
{
    const size_t i = ((size_t)blockIdx.x*256 + threadIdx.x)*8;
    const float4 a = *(const float4*)&X[i];
    const float4 b = *(const float4*)&X[i+4];
    __align__(16) unsigned short t[8] = { f2bf(a.x), f2bf(a.y), f2bf(a.z), f2bf(a.w),
                                          f2bf(b.x), f2bf(b.y), f2bf(b.z), f2bf(b.w) };
    *(u32x4*)&Xb[i] = *(u32x4*)t;
}

// ---------------------------------------------------------------------------
// Bgt[n][k] = (n<1024 ? Wgre : Wgim)[k][n&1023]  -- bf16, [2048][1024]
// ---------------------------------------------------------------------------
__global__ __launch_bounds__(256) void wprep_g_kernel(
    const float* __restrict__ Wgre, const float* __restrict__ Wgim,
    unsigned short* __restrict__ Bgt)
{
    const int n0 = blockIdx.x*64, k0 = blockIdx.y*64;
    const float* src = (n0 < HIDDEN) ? Wgre : Wgim;
    const int nc = n0 & (HIDDEN-1);
    __shared__ float Ws[64][65];
    const int tid = threadIdx.x;
    #pragma unroll
    for (int it = 0; it < 4; ++it) {
        const int r = (tid >> 4) + it*16, c = (tid & 15)*4;
        *(float4*)&Ws[r][c] = *(const float4*)&src[(size_t)(k0 + r)*HIDDEN + nc + c];
    }
    __syncthreads();
    const int nl = tid >> 2, seg = (tid & 3)*16;
    __align__(16) unsigned short t[16];
    #pragma unroll
    for (int j = 0; j < 16; ++j) t[j] = f2bf(Ws[seg + j][nl]);
    u32x4* d = (u32x4*)&Bgt[(size_t)(n0 + nl)*HIDDEN + k0 + seg];
    d[0] = ((u32x4*)t)[0];
    d[1] = ((u32x4*)t)[1];
}

// ---------------------------------------------------------------------------
// Bot[n][k] (bf16, [1024][2048]):
//   imMode=0: k<1024 ?  Wore[k][n] : -Woim[k-1024][n]   (real-part weights)
//   imMode=1: k<1024 ?  Woim[k][n] :  Wore[k-1024][n]   (imag-part weights)
// ---------------------------------------------------------------------------
__global__ __launch_bounds__(256) void wprep_o_kernel(
    const float* __restrict__ Wore, const float* __restrict__ Woim,
    unsigned short* __restrict__ Bot, const int imMode)
{
    const int n0 = blockIdx.x*64, k0 = blockIdx.y*64;
    const float* src;
    float sign = 1.0f;
    if (!imMode) { if (k0 < HIDDEN) src = Wore; else { src = Woim; sign = -1.0f; } }
    else         { src = (k0 < HIDDEN) ? Woim : Wore; }
    const int kc = k0 & (HIDDEN-1);
    __shared__ float Ws[64][65];
    const int tid = threadIdx.x;
    #pragma unroll
    for (int it = 0; it < 4; ++it) {
        const int r = (tid >> 4) + it*16, c = (tid & 15)*4;
        const float4 v = *(const float4*)&src[(size_t)(kc + r)*HIDDEN + n0 + c];
        Ws[r][c+0] = v.x*sign; Ws[r][c+1] = v.y*sign; Ws[r][c+2] = v.z*sign; Ws[r][c+3] = v.w*sign;
    }
    __syncthreads();
    const int nl = tid >> 2, seg = (tid & 3)*16;
    __align__(16) unsigned short t[16];
    #pragma unroll
    for (int j = 0; j < 16; ++j) t[j] = f2bf(Ws[seg + j][nl]);
    u32x4* d = (u32x4*)&Bot[(size_t)(n0 + nl)*(2*HIDDEN) + k0 + seg];
    d[0] = ((u32x4*)t)[0];
    d[1] = ((u32x4*)t)[1];
}

// ---------------------------------------------------------------------------
// generic bf16 MFMA GEMM: C[M][N] = A[M][K] @ Bt[N][K]^T
// 128x128 tile, BK=64, 4 waves (2x2 of 32x32x16 frags each).
// mode 0: plain fp32 store; mode 1/2: interleaved complex re/im store.
// ---------------------------------------------------------------------------
__global__ __launch_bounds__(256) void gemm_bf16_kernel(
    const unsigned short* __restrict__ A,
    const unsigned short* __restrict__ Bt,
    float* __restrict__ C,
    const int K, const int N, const int mode)
{
    __shared__ __align__(16) unsigned short As[128][72];
    __shared__ __align__(16) unsigned short Bs[128][72];

    const int tid = threadIdx.x;
    const int mb = blockIdx.x, nb = blockIdx.y;
    const int lane = tid & 63, w = tid >> 6;
    const int l31 = lane & 31, hi = lane >> 5;
    const int wm = (w >> 1) * 64, wn = (w & 1) * 64;

    const int srow = tid >> 2;          // 0..63
    const int sseg = (tid & 3) * 16;    // 0,16,32,48 (full 64-col tile)

    const unsigned short* ga = A  + (size_t)(mb*128 + srow)*K + sseg;
    const unsigned short* gb = Bt + (size_t)(nb*128 + srow)*K + sseg;

    f32x16 acc00, acc01, acc10, acc11;
    #pragma unroll
    for (int e = 0; e < 16; ++e) { acc00[e]=0.f; acc01[e]=0.f; acc10[e]=0.f; acc11[e]=0.f; }

    u32x4 ra0 = *(const u32x4*)(ga);
    u32x4 ra1 = *(const u32x4*)(ga + 8);
    u32x4 ra2 = *(const u32x4*)(ga + (size_t)64*K);
    u32x4 ra3 = *(const u32x4*)(ga + (size_t)64*K + 8);
    u32x4 rb0 = *(const u32x4*)(gb);
    u32x4 rb1 = *(const u32x4*)(gb + 8);
    u32x4 rb2 = *(const u32x4*)(gb + (size_t)64*K);
    u32x4 rb3 = *(const u32x4*)(gb + (size_t)64*K + 8);

    for (int kk = 0; kk < K; kk += 64) {
        __syncthreads();
        *(u32x4*)&As[srow][sseg]          = ra0;
        *(u32x4*)&As[srow][sseg + 8]      = ra1;
        *(u32x4*)&As[srow + 64][sseg]     = ra2;
        *(u32x4*)&As[srow + 64][sseg + 8] = ra3;
        *(u32x4*)&Bs[srow][sseg]          = rb0;
        *(u32x4*)&Bs[srow][sseg + 8]      = rb1;
        *(u32x4*)&Bs[srow + 64][sseg]     = rb2;
        *(u32x4*)&Bs[srow + 64][sseg + 8] = rb3;
        if (kk + 64 < K) {
            const int o = kk + 64;
            ra0 = *(const u32x4*)(ga + o);
            ra1 = *(const u32x4*)(ga + o + 8);
            ra2 = *(const u32x4*)(ga + (size_t)64*K + o);
            ra3 = *(const u32x4*)(ga + (size_t)64*K + o + 8);
            rb0 = *(const u32x4*)(gb + o);
            rb1 = *(const u32x4*)(gb + o + 8);
            rb2 = *(const u32x4*)(gb + (size_t)64*K + o);
            rb3 = *(const u32x4*)(gb + (size_t)64*K + o + 8);
        }
        __syncthreads();
        #pragma unroll
        for (int ks = 0; ks < 4; ++ks) {
            Frag a0, a1, b0, b1;
            a0.u = *(const u32x4*)&As[wm + l31     ][ks*16 + hi*8];
            a1.u = *(const u32x4*)&As[wm + l31 + 32][ks*16 + hi*8];
            b0.u = *(const u32x4*)&Bs[wn + l31     ][ks*16 + hi*8];
            b1.u = *(const u32x4*)&Bs[wn + l31 + 32][ks*16 + hi*8];
            acc00 = __builtin_amdgcn_mfma_f32_32x32x16_bf16(a0.h, b0.h, acc00, 0, 0, 0);
            acc01 = __builtin_amdgcn_mfma_f32_32x32x16_bf16(a0.h, b1.h, acc01, 0, 0, 0);
            acc10 = __builtin_amdgcn_mfma_f32_32x32x16_bf16(a1.h, b0.h, acc10, 0, 0, 0);
            acc11 = __builtin_amdgcn_mfma_f32_32x32x16_bf16(a1.h, b1.h, acc11, 0, 0, 0);
        }
    }

    const int cb = nb*128 + wn + l31;
    #pragma unroll
    for (int i = 0; i < 2; ++i) {
        const f32x16& c0 = i ? acc10 : acc00;
        const f32x16& c1 = i ? acc11 : acc01;
        #pragma unroll
        for (int r = 0; r < 16; ++r) {
            const int row = mb*128 + wm + 32*i + (r & 3) + 8*(r >> 2) + 4*hi;
            if (mode == 0) {
                float* cr = C + (size_t)row*N + cb;
                cr[0]  = c0[r];
                cr[32] = c1[r];
            } else {
                float* cr = C + ((size_t)row*N + cb)*2 + (mode - 1);
                cr[0]  = c0[r];
                cr[64] = c1[r];
            }
        }
    }
}

// ---------------------------------------------------------------------------
// fused: group-norm(Y) + swish(G) + add -> Aout bf16 [2048][2048] (Zr | Zi)
// ---------------------------------------------------------------------------
__global__ __launch_bounds__(256) void znorm_kernel(
    const float* __restrict__ yre, const float* __restrict__ yim,
    const float* __restrict__ Graw,
    const float* __restrict__ w, const float* __restrict__ bbv,
    unsigned short* __restrict__ Aout)
{
    const int row  = blockIdx.x;
    const int wv   = threadIdx.x >> 6;
    const int lane = threadIdx.x & 63;

    #pragma unroll
    for (int gi = 0; gi < 2; ++gi) {
        const int h = wv*2 + gi;
        const size_t base = (size_t)row*HIDDEN + h*DHEAD;

        const float r0 = yre[base + lane];
        const float r1 = yre[base + lane + 64];
        const float i0 = yim[base + lane];
        const float i1 = yim[base + lane + 64];

        float sr = r0 + r1, si = i0 + i1;
        #pragma unroll
        for (int off = 32; off > 0; off >>= 1) {
            sr += __shfl_xor(sr, off);
            si += __shfl_xor(si, off);
        }
        const float mr = sr * (1.0f/128.0f), mi = si * (1.0f/128.0f);
        const float d0r = r0 - mr, d1r = r1 - mr, d0i = i0 - mi, d1i = i1 - mi;
        float vs = d0r*d0r + d0i*d0i + d1r*d1r + d1i*d1i;
        #pragma unroll
        for (int off = 32; off > 0; off >>= 1) vs += __shfl_xor(vs, off);
        const float scale = 1.0f / sqrtf(vs * (1.0f/127.0f) + GEPS);

        const float w0 = w[h*DHEAD + lane],   w1 = w[h*DHEAD + lane + 64];
        const float b0 = bbv[h*DHEAD + lane], b1 = bbv[h*DHEAD + lane + 64];
        const float zr0 = fmaf(d0r*scale, w0, b0);
        const float zr1 = fmaf(d1r*scale, w1, b1);
        const float zi0 = d0i*scale*w0;
        const float zi1 = d1i*scale*w1;

        const int col = h*DHEAD + lane;
        const size_t gbase = (size_t)row*(2*HIDDEN);
        const float gr0 = Graw[gbase + col];
        const float gr1 = Graw[gbase + col + 64];
        const float gi0 = Graw[gbase + HIDDEN + col];
        const float gi1 = Graw[gbase + HIDDEN + col + 64];

        float s0r, s0i, s1r, s1i;
        cswish(gr0, gi0, s0r, s0i);
        cswish(gr1, gi1, s1r, s1i);

        Aout[gbase + col]               = f2bf(s0r + zr0);
        Aout[gbase + col + 64]          = f2bf(s1r + zr1);
        Aout[gbase + HIDDEN + col]      = f2bf(s0i + zi0);
        Aout[gbase + HIDDEN + col + 64] = f2bf(s1i + zi1);
    }
}

// ---------------------------------------------------------------------------
extern "C" void kernel_launch(void* const* d_in, const int* in_sizes, int n_in,
                              void* d_out, int out_size, void* d_ws, size_t ws_size,
                              hipStream_t stream)
{
    (void)in_sizes; (void)n_in; (void)ws_size;

    const float* X     = (const float*)d_in[0];
    const float* Wq    = (const float*)d_in[1];
    const float* Wk    = (const float*)d_in[2];
    const float* Wv    = (const float*)d_in[3];
    const float* theta = (const float*)d_in[4];
    const float* gnw   = (const float*)d_in[5];
    const float* gnb   = (const float*)d_in[6];
    const float* Wgre  = (const float*)d_in[7];
    const float* Wgim  = (const float*)d_in[8];
    const float* Wore  = (const float*)d_in[9];
    const float* Woim  = (const float*)d_in[10];

    float* ws = (float*)d_ws;
    const size_t P = (size_t)NTOK*HIDDEN;          // 2M elements

    float* yre = ws;                               // [0, P)
    float* yim = ws + P;                           // [P, 2P)
    unsigned short* Qbre = (unsigned short*)(ws + 2*P);  // [2P,4P) as 4 x P ushort
    unsigned short* Qbim = Qbre + P;
    unsigned short* Kbre = Qbim + P;
    unsigned short* Kbim = Kbre + P;
    float* Graw = ws + 2*P;                        // alias Q/K (dead after attn), [2P,4P)
    float* vv   = ws + 4*P;                        // [4P,5P)
    unsigned short* Aout = (unsigned short*)(ws + 4*P);  // alias vv (dead after vt)
    unsigned short* Vtb  = (unsigned short*)(ws + 5*P);  // [5P,5.5P)
    unsigned short* Bot  = Vtb;                    // alias Vtb (dead after attn)
    unsigned short* Xb   = (unsigned short*)(ws + 5*P) + P;      // [5.5P,6P)
    unsigned short* Bgt  = (unsigned short*)(ws + 6*P);          // [6P,6.5P)
    unsigned short* Boti = (unsigned short*)(ws + 6*P) + P;      // [6.5P,7P) cplx only
    float* gpw = ws + 7*P;

    const int cplx = (out_size >= (int)(2*P)) ? 1 : 0;

    hipLaunchKernelGGL(gpow_kernel, dim3(NHEADS), dim3(SEQ), 0, stream, gpw);
    hipLaunchKernelGGL(proj_kernel, dim3(NTOK/64, NHEADS, 3), dim3(256), 0, stream,
                       X, Wq, Wk, Wv, theta, Qbre, Qbim, Kbre, Kbim, vv);
    hipLaunchKernelGGL(vt_kernel, dim3(NTOK/64, NHEADS), dim3(256), 0, stream, vv, Vtb);
    hipLaunchKernelGGL(attn_kernel, dim3(SEQ/32 * BATCH*NHEADS), dim3(128), 0, stream,
                       Qbre, Qbim, Kbre, Kbim, Vtb, gpw, yre, yim);

    // gating path (after attn: Graw aliases Q/K)
    hipLaunchKernelGGL(xprep_kernel, dim3(NTOK*HIDDEN/(256*8)), dim3(256), 0, stream, X, Xb);
    hipLaunchKernelGGL(wprep_g_kernel, dim3(2*HIDDEN/64, HIDDEN/64), dim3(256), 0, stream,
                       Wgre, Wgim, Bgt);
    hipLaunchKernelGGL(gemm_bf16_kernel, dim3(NTOK/128, 2*HIDDEN/128), dim3(256), 0, stream,
                       Xb, Bgt, Graw, HIDDEN, 2*HIDDEN, 0);

    // fused norm + swish + add -> bf16 A
    hipLaunchKernelGGL(znorm_kernel, dim3(NTOK), dim3(256), 0, stream,
                       yre, yim, Graw, gnw, gnb, Aout);

    // output projection
    hipLaunchKernelGGL(wprep_o_kernel, dim3(HIDDEN/64, 2*HIDDEN/64), dim3(256), 0, stream,
                       Wore, Woim, Bot, 0);
    if (!cplx) {
        hipLaunchKernelGGL(gemm_bf16_kernel, dim3(NTOK/128, HIDDEN/128), dim3(256), 0, stream,
                           Aout, Bot, (float*)d_out, 2*HIDDEN, HIDDEN, 0);
    } else {
        hipLaunchKernelGGL(wprep_o_kernel, dim3(HIDDEN/64, 2*HIDDEN/64), dim3(256), 0, stream,
                           Wore, Woim, Boti, 1);
        hipLaunchKernelGGL(gemm_bf16_kernel, dim3(NTOK/128, HIDDEN/128), dim3(256), 0, stream,
                           Aout, Bot, (float*)d_out, 2*HIDDEN, HIDDEN, 1);
        hipLaunchKernelGGL(gemm_bf16_kernel, dim3(NTOK/128, HIDDEN/128), dim3(256), 0, stream,
                           Aout, Boti, (float*)d_out, 2*HIDDEN, HIDDEN, 2);
    }
}